// Round 5
// baseline (1387.908 us; speedup 1.0000x reference)
//
#include <hip/hip_runtime.h>
#include <hip/hip_bf16.h>

// ---------------------------------------------------------------------------
// Segment_3DCenter round 4: conv2/conv3 MFMA f16 hi/lo split, restructured:
// h-pair blocks (512 thr, 8 waves = 2 h x 4 w-groups), 4x13 panel staging,
// 2 blocks/CU x 8 waves = 16 waves/CU. al loads hoisted; zeropad fused into
// conv1/conv2 epilogues.
// pk layout: pk[b][p][rawd 134][ic 16] u32 ({hi,lo} f16 pair, x256 scale).
// ---------------------------------------------------------------------------

#define F_SLICE (64 * 16 * 121)  // 123904
#define PK_ELEMS (64 * 121 * 134 * 16)
#define PSTR 18672  // LDS part stride (halves): 52*352 + guard 368

typedef _Float16 half8 __attribute__((ext_vector_type(8)));
typedef float float4v __attribute__((ext_vector_type(4)));

union HU { _Float16 h; unsigned short u; };

__device__ inline unsigned pack_pair(float sv) {
  float s = sv * 256.f;
  _Float16 hi = (_Float16)s;
  _Float16 lo = (_Float16)(s - (float)hi);
  HU a, c; a.h = hi; c.h = lo;
  return (unsigned)a.u | ((unsigned)c.u << 16);
}

// ---------------- transpose x: [b][c][p] -> [b][p][c], LDS-tiled -----------
__global__ __launch_bounds__(256) void transpose_kernel(
    const float* __restrict__ x, float* __restrict__ x_t) {
  __shared__ float tile[128][123];
  int b = blockIdx.x, t = threadIdx.x;
  const float* xb = x + (size_t)b * 128 * 121;
  for (int idx = t; idx < 128 * 121; idx += 256) {
    int c = idx / 121, p = idx - c * 121;
    tile[c][p] = xb[idx];
  }
  __syncthreads();
  float* ob = x_t + (size_t)b * 121 * 128;
  for (int idx = t; idx < 121 * 128; idx += 256) {
    int p = idx >> 7, c = idx & 127;
    ob[idx] = tile[c][p];
  }
}

// ---------------- softmax over last dim of cpr_w (48 rows x 128) -----------
__global__ __launch_bounds__(128) void softmax_kernel(
    const float* __restrict__ w, float* __restrict__ a) {
  int row = blockIdx.x, t = threadIdx.x;
  __shared__ float red[128];
  float v = w[row * 128 + t];
  red[t] = v;
  __syncthreads();
  for (int s = 64; s; s >>= 1) {
    if (t < s) red[t] = fmaxf(red[t], red[t + s]);
    __syncthreads();
  }
  float m = red[0];
  __syncthreads();
  float e = expf(v - m);
  red[t] = e;
  __syncthreads();
  for (int s = 64; s; s >>= 1) {
    if (t < s) red[t] += red[t + s];
    __syncthreads();
  }
  a[row * 128 + t] = e / red[0];
}

// ---------------- repack conv1 weights (fp32 path) -------------------------
__global__ __launch_bounds__(256) void repack1_kernel(
    const float* __restrict__ w3d1, float* __restrict__ wrep1) {
  int r = blockIdx.x * 256 + threadIdx.x;
  if (r < 1008) {
    int j = r;
    int kw = j % 3; j /= 3;
    int o = j % 8; j /= 8;
    int kh = j % 3; j /= 3;
    int kd = j % 7; j /= 7;
    int gg = j;
    wrep1[r] = w3d1[(gg * 8 + o) * 63 + kd * 9 + kh * 3 + kw];
  }
}

// ---------------- repack conv2/3 weights into MFMA A-frag layout -----------
// arep[cv 2][chunk 32][part 2][lane 64][j 8] f16, scaled x256.
__global__ __launch_bounds__(256) void arep_kernel(
    const float* __restrict__ w3d23, unsigned short* __restrict__ arep) {
  int idx = blockIdx.x * 256 + threadIdx.x;  // 0..65535
  int j = idx & 7;
  int lane = (idx >> 3) & 63;
  int part = (idx >> 9) & 1;
  int chunk = (idx >> 10) & 31;
  int cv = idx >> 15;
  int m = lane & 15, qq = lane >> 4;
  int e = chunk * 2 + (qq >> 1);
  int ic = (qq & 1) * 8 + j;
  float w = 0.f;
  if (e < 63) {
    int kd = e / 9, kh = (e % 9) / 3, kw = e % 3;
    w = w3d23[((cv * 16 + m) * 16 + ic) * 63 + kd * 9 + kh * 3 + kw] * 256.f;
  }
  _Float16 hi = (_Float16)w;
  HU out;
  out.h = (part == 0) ? hi : (_Float16)(w - (float)hi);
  arep[idx] = out.u;
}

// ---------------- conv1 (ic=1) fp32: x_t -> pk1 (+fused cpr f1, d-halo) ----
__global__ __launch_bounds__(256, 4) void conv1_kernel(
    const float* __restrict__ in, const float* __restrict__ wrep,
    const float* __restrict__ bias, const float* __restrict__ al,
    unsigned int* __restrict__ pkout, float* __restrict__ f_out) {
  __shared__ float in_lds[18][134];
  __shared__ float red[2][16][4];
  const int t = threadIdx.x;
  const int bx = blockIdx.x;
  const int b = blockIdx.y;
  const int h = bx / 3;
  const int w0 = (bx % 3) * 4;
  const int lane = t & 63;
  const int wv = t >> 6;
  const int dh = wv & 1;
  const int dd = lane + (dh << 6);
  const int g = __builtin_amdgcn_readfirstlane(wv >> 1);
  const int oc_base = g << 3;

  float acc[8][4];
#pragma unroll
  for (int o = 0; o < 8; ++o)
#pragma unroll
    for (int c = 0; c < 4; ++c) acc[o][c] = 0.f;

  const int ds = t & 127;
  const int half = t >> 7;

  for (int r = half; r < 18; r += 2) {
    int hr = r / 6;
    int wc = r - hr * 6;
    int hh = h - 1 + hr;
    int ww = w0 - 1 + wc;
    bool ok = (hh >= 0) & (hh < 11) & (ww >= 0) & (ww < 11);
    const float* src = in + (((size_t)b) * 121 + hh * 11 + ww) * 128;
    float v = 0.f;
    if (ok && ds >= 3) v = src[ds - 3];
    in_lds[r][ds] = v;
    if (ds < 6) {
      float v2 = 0.f;
      if (ok && ds < 3) v2 = src[125 + ds];
      in_lds[r][128 + ds] = v2;
    }
  }
  __syncthreads();
  const float* wbase = wrep + g * 504;
#pragma unroll
  for (int kd = 0; kd < 7; ++kd) {
#pragma unroll
    for (int kh = 0; kh < 3; ++kh) {
      float ws[24];
      const float* wp = wbase + kd * 72 + kh * 24;
#pragma unroll
      for (int j = 0; j < 24; ++j) ws[j] = wp[j];
      float v[6];
#pragma unroll
      for (int qq = 0; qq < 6; ++qq) v[qq] = in_lds[kh * 6 + qq][dd + kd];
#pragma unroll
      for (int o = 0; o < 8; ++o)
#pragma unroll
        for (int kw = 0; kw < 3; ++kw) {
          float wv_ = ws[o * 3 + kw];
#pragma unroll
          for (int c = 0; c < 4; ++c)
            acc[o][c] = fmaf(wv_, v[kw + c], acc[o][c]);
        }
    }
  }

  const int p0 = h * 11 + w0;
  float alv[8];
#pragma unroll
  for (int o = 0; o < 8; ++o) alv[o] = al[(oc_base + o) * 128 + dd];
#pragma unroll
  for (int o = 0; o < 8; ++o) {
    float bv = bias[oc_base + o];
#pragma unroll
    for (int c = 0; c < 4; ++c) {
      float sv = fmaxf(acc[o][c] + bv, 0.f);
      if (w0 + c < 11)
        pkout[(((size_t)b * 121 + p0 + c) * 134 + dd + 3) * 16 + oc_base + o] =
            pack_pair(sv);
      float pv = sv * alv[o];
#pragma unroll
      for (int off = 32; off; off >>= 1) pv += __shfl_down(pv, off, 64);
      if (lane == 0) red[dh][oc_base + o][c] = pv;
    }
  }
  // fused d-halo zeroing (replaces zeropad kernel for pk1)
  if (dd < 3) {
#pragma unroll
    for (int c = 0; c < 4; ++c) {
      if (w0 + c < 11) {
        size_t b0 = (((size_t)b * 121 + p0 + c) * 134 + dd) * 16 + oc_base;
        size_t b1 = (((size_t)b * 121 + p0 + c) * 134 + 131 + dd) * 16 + oc_base;
#pragma unroll
        for (int o = 0; o < 8; ++o) { pkout[b0 + o] = 0u; pkout[b1 + o] = 0u; }
      }
    }
  }
  __syncthreads();
  if (t < 64) {
    int oc = t >> 2, c = t & 3;
    if (w0 + c < 11)
      f_out[((size_t)b * 16 + oc) * 121 + p0 + c] =
          fmaxf(red[0][oc][c] + red[1][oc][c], 0.f);
  }
}

// ---------------- conv2/conv3: MFMA f16x2-split, h-pair blocks -------------
// Block = (h-pair bx, b), 512 thr = 8 waves: hs = wave>>2 (h sub-row),
// wg = wave&3 (w-triple). Stages 4 rows x 13 cols x 22 d x 16 ic per d16.
// LDS: lds2[part 2][panel 52][ich 2][d 22][ic8] halves, part stride PSTR
// (incl. guard for dummy-pixel reads).
template <bool WRITE_PK>
__global__ __launch_bounds__(512, 4) void conv_mfma_kernel(
    const unsigned int* __restrict__ pkin,
    const unsigned short* __restrict__ arep, const float* __restrict__ bias,
    const float* __restrict__ al, unsigned int* __restrict__ pkout,
    float* __restrict__ f_out) {
  __shared__ _Float16 lds2[2][PSTR];
  const int t = threadIdx.x;
  const int bx = blockIdx.x, b = blockIdx.y;
  const int lane = t & 63, wave = t >> 6;
  const int n = lane & 15, q = lane >> 4;
  const int hs = wave >> 2, wg = wave & 3;
  const int h = 2 * bx + hs;  // 0..11 (11 = dummy)

  // staging descriptors: 4576 uint4-units = 52 panels x 22 d x 4 ic-quads
  int gbase[9], lbase[9];
#pragma unroll
  for (int i = 0; i < 9; ++i) {
    int u = t + i * 512;
    if (u < 4576) {
      int q4 = u & 3;
      int rem = u >> 2;
      int panel = rem / 22;
      int dloc = rem - panel * 22;
      int rr = panel / 13, cc = panel - rr * 13;
      int hh = 2 * bx + rr - 1, ww = cc - 1;
      bool ok = (hh >= 0) & (hh < 11) & (ww >= 0) & (ww < 11);
      lbase[i] = panel * 352 + (q4 >> 1) * 176 + dloc * 8 + (q4 & 1) * 4;
      gbase[i] = ok ? (((b * 121 + hh * 11 + ww) * 134 + dloc) * 16 + q4 * 4)
                    : -1;
    } else {
      lbase[i] = -1;
      gbase[i] = -1;
    }
  }
  // zero invalid units once; valid units overwritten every d16
#pragma unroll
  for (int i = 0; i < 9; ++i) {
    if (lbase[i] >= 0 && gbase[i] < 0) {
      uint2 z; z.x = 0u; z.y = 0u;
      *(uint2*)&lds2[0][lbase[i]] = z;
      *(uint2*)&lds2[1][lbase[i]] = z;
    }
  }

  float bias_r[4];
#pragma unroll
  for (int r = 0; r < 4; ++r) bias_r[r] = bias[q * 4 + r];

  const int bbase = (q & 1) * 176 + n * 8;
  float facc[3][4];
#pragma unroll
  for (int tt = 0; tt < 3; ++tt)
#pragma unroll
    for (int r = 0; r < 4; ++r) facc[tt][r] = 0.f;

  for (int d16 = 0; d16 < 8; ++d16) {
    __syncthreads();
#pragma unroll
    for (int i = 0; i < 9; ++i) {
      if (gbase[i] >= 0) {
        uint4 v = *(const uint4*)&pkin[gbase[i] + d16 * 256];
        uint2 hv, lv;
        hv.x = (v.x & 0xffffu) | (v.y << 16);
        hv.y = (v.z & 0xffffu) | (v.w << 16);
        lv.x = (v.x >> 16) | (v.y & 0xffff0000u);
        lv.y = (v.z >> 16) | (v.w & 0xffff0000u);
        *(uint2*)&lds2[0][lbase[i]] = hv;
        *(uint2*)&lds2[1][lbase[i]] = lv;
      }
    }
    // hoisted al loads for this d16 (consumed in epilogue)
    float alr[4];
#pragma unroll
    for (int r = 0; r < 4; ++r) alr[r] = al[(q * 4 + r) * 128 + d16 * 16 + n];
    __syncthreads();

    float4v acc[3];
#pragma unroll
    for (int tt = 0; tt < 3; ++tt) acc[tt] = (float4v){0.f, 0.f, 0.f, 0.f};

#pragma unroll
    for (int c = 0; c < 32; ++c) {
      const int e0 = 2 * c, e1r = 2 * c + 1;
      const int e0c = (e0 > 62) ? 62 : e0;
      const int e1 = (e1r > 62) ? 62 : e1r;
      const int sel0 =
          ((hs + (e0c % 9) / 3) * 13 + (e0c % 3)) * 352 + (e0c / 9) * 8;
      const int sel1 =
          ((hs + (e1 % 9) / 3) * 13 + (e1 % 3)) * 352 + (e1 / 9) * 8;
      const int sel = (lane & 32) ? sel1 : sel0;
      half8 ahi = *(const half8*)&arep[((c * 2 + 0) * 64 + lane) * 8];
      half8 alo = *(const half8*)&arep[((c * 2 + 1) * 64 + lane) * 8];
#pragma unroll
      for (int tt = 0; tt < 3; ++tt) {
        const int wl = wg * 3 + tt;  // 0..11 (11 dummy)
        const _Float16* ph = &lds2[0][bbase + sel + wl * 352];
        half8 bhi = *(const half8*)ph;
        half8 blo = *(const half8*)(ph + PSTR);
        acc[tt] = __builtin_amdgcn_mfma_f32_16x16x32_f16(ahi, bhi, acc[tt], 0, 0, 0);
        acc[tt] = __builtin_amdgcn_mfma_f32_16x16x32_f16(ahi, blo, acc[tt], 0, 0, 0);
        acc[tt] = __builtin_amdgcn_mfma_f32_16x16x32_f16(alo, bhi, acc[tt], 0, 0, 0);
      }
    }

    // epilogue for this d16
#pragma unroll
    for (int tt = 0; tt < 3; ++tt) {
      const int wl = wg * 3 + tt;
      if (h < 11 && wl < 11) {
        const int p = h * 11 + wl;
        unsigned pkarr[4];
#pragma unroll
        for (int r = 0; r < 4; ++r) {
          float sv = fmaxf(acc[tt][r] * (1.f / 65536.f) + bias_r[r], 0.f);
          if (WRITE_PK) pkarr[r] = pack_pair(sv);
          facc[tt][r] += sv * alr[r];
        }
        if (WRITE_PK) {
          uint4 pkv;
          pkv.x = pkarr[0]; pkv.y = pkarr[1]; pkv.z = pkarr[2]; pkv.w = pkarr[3];
          *(uint4*)&pkout[(((size_t)b * 121 + p) * 134 + d16 * 16 + n + 3) * 16 +
                          q * 4] = pkv;
          // fused d-halo zeroing for pk2
          if (d16 == 0 && n < 3) {
            uint4 z = {0u, 0u, 0u, 0u};
            *(uint4*)&pkout[(((size_t)b * 121 + p) * 134 + n) * 16 + q * 4] = z;
          }
          if (d16 == 7 && n >= 13) {
            uint4 z = {0u, 0u, 0u, 0u};
            *(uint4*)&pkout[(((size_t)b * 121 + p) * 134 + n + 118) * 16 +
                            q * 4] = z;
          }
        }
      }
    }
  }

  // fused cpr: reduce facc over the 16 n-lanes of each quad-group
#pragma unroll
  for (int tt = 0; tt < 3; ++tt) {
    const int wl = wg * 3 + tt;
#pragma unroll
    for (int r = 0; r < 4; ++r) {
      float v = facc[tt][r];
      v += __shfl_xor(v, 1, 64);
      v += __shfl_xor(v, 2, 64);
      v += __shfl_xor(v, 4, 64);
      v += __shfl_xor(v, 8, 64);
      if (n == 0 && h < 11 && wl < 11)
        f_out[((size_t)b * 16 + q * 4 + r) * 121 + h * 11 + wl] =
            fmaxf(v, 0.f);
    }
  }
}

// ---------------- both 16->16 2D convs (3x3 pad1 + relu), fused ------------
__global__ __launch_bounds__(128) void conv2d2_kernel(
    const float* __restrict__ fin, const float* __restrict__ wgt,
    const float* __restrict__ bias, float* __restrict__ f4,
    float* __restrict__ f5) {
  const int b = blockIdx.x, t = threadIdx.x;
  __shared__ float buf0[16 * 121];
  __shared__ float buf1[16 * 121];
  const float* fb = fin + (size_t)b * 16 * 121;
  for (int idx = t; idx < 16 * 121; idx += 128) buf0[idx] = fb[idx];
  __syncthreads();
  for (int layer = 0; layer < 2; ++layer) {
    const float* src = layer ? buf1 : buf0;
    float* dst = layer ? nullptr : buf1;
    const float* wl = wgt + layer * 2304;
    const float* bl = bias + layer * 16;
    float* go = (layer ? f5 : f4) + (size_t)b * 16 * 121;
    if (t < 121) {
      int h = t / 11, w = t - h * 11;
      float acc[16];
#pragma unroll
      for (int o = 0; o < 16; ++o) acc[o] = bl[o];
      for (int ic = 0; ic < 16; ++ic) {
#pragma unroll
        for (int u = 0; u < 3; ++u) {
          int hh = h + u - 1;
#pragma unroll
          for (int v = 0; v < 3; ++v) {
            int ww = w + v - 1;
            float val = (hh >= 0 && hh < 11 && ww >= 0 && ww < 11)
                            ? src[ic * 121 + hh * 11 + ww]
                            : 0.f;
            const float* wp = wl + ic * 9 + u * 3 + v;
#pragma unroll
            for (int o = 0; o < 16; ++o)
              acc[o] = fmaf(val, wp[o * 144], acc[o]);
          }
        }
      }
#pragma unroll
      for (int o = 0; o < 16; ++o) {
        float r = fmaxf(acc[o], 0.f);
        go[o * 121 + t] = r;
        if (dst) dst[o * 121 + t] = r;
      }
    }
    __syncthreads();
  }
}

// ---------------- sp path: seg conv -> top5 -> patch convs -> side ---------
__global__ __launch_bounds__(128) void sp_prep_kernel(
    const float* __restrict__ f_all, const float* __restrict__ x_t,
    const float* __restrict__ seg_w, const float* __restrict__ seg_b,
    const float* __restrict__ sp_wa, const float* __restrict__ sp_ba,
    const float* __restrict__ sp_wb, const float* __restrict__ sp_bb,
    const float* __restrict__ sp_sw, const float* __restrict__ sp_sb,
    float* __restrict__ sp_sd) {
  const int b = blockIdx.x, i = blockIdx.y;
  const int t = threadIdx.x;
  __shared__ float fl[16 * 121];
  __shared__ float act[121];
  __shared__ float diffs[121];
  __shared__ int sel[5];
  __shared__ float s7[7], xc7[7];
  __shared__ float P[2][7][7];
  __shared__ float y1[16][9];
  __shared__ float y2[16];

  const float* fb = f_all + ((size_t)i * 64 + b) * 16 * 121;
  for (int idx = t; idx < 16 * 121; idx += 128) fl[idx] = fb[idx];
  __syncthreads();

  if (t < 121) {
    int h = t / 11, w = t - h * 11;
    float a = seg_b[i];
    const float* sw = seg_w + i * 144;
#pragma unroll
    for (int u = 0; u < 3; ++u) {
      int hh = h + u - 1;
#pragma unroll
      for (int v = 0; v < 3; ++v) {
        int ww = w + v - 1;
        if (hh >= 0 && hh < 11 && ww >= 0 && ww < 11) {
          int pp = hh * 11 + ww;
          for (int ic = 0; ic < 16; ++ic)
            a = fmaf(fl[ic * 121 + pp], sw[ic * 9 + u * 3 + v], a);
        }
      }
    }
    act[t] = a;
  }
  __syncthreads();
  if (t < 121) diffs[t] = fabsf(act[t] - act[60]);
  __syncthreads();

  for (int k = 0; k < 5; ++k) {
    if (t < 64) {
      float d0 = diffs[t];
      int i0 = t;
      float d1 = (t + 64 < 121) ? diffs[t + 64] : 3.0e38f;
      if (d1 < d0) { d0 = d1; i0 = t + 64; }
#pragma unroll
      for (int off = 32; off; off >>= 1) {
        float od = __shfl_down(d0, off, 64);
        int oi = __shfl_down(i0, off, 64);
        if (od < d0 || (od == d0 && oi < i0)) { d0 = od; i0 = oi; }
      }
      if (t == 0) {
        sel[k] = i0;
        diffs[i0] = 3.0e38f;
      }
    }
    __syncthreads();
  }

  if (t < 7) {
    const float* xb = x_t + (size_t)b * 121 * 128;
    float s = 0.f;
    for (int k = 0; k < 5; ++k) s += xb[(size_t)sel[k] * 128 + 61 + t];
    s7[t] = s;
    xc7[t] = xb[60 * 128 + 61 + t];
  }
  __syncthreads();
  if (t < 49) {
    int r = t / 7, c = t - r * 7;
    float d0 = s7[c];
    if (fabsf(d0) < 0.01f) d0 = 0.01f;
    float d1 = xc7[c];
    if (fabsf(d1) < 0.01f) d1 = 0.01f;
    P[0][r][c] = s7[r] / d0;
    P[1][r][c] = xc7[r] / d1;
  }
  __syncthreads();
  for (int item = t; item < 144; item += 128) {
    int ch = item / 9, pos = item - ch * 9;
    int a0 = pos / 3, b0 = pos - a0 * 3;
    float a = sp_ba[i * 16 + ch];
    const float* wa = sp_wa + ((size_t)(i * 16 + ch) * 2) * 9;
#pragma unroll
    for (int icc = 0; icc < 2; ++icc)
#pragma unroll
      for (int u = 0; u < 3; ++u)
#pragma unroll
        for (int v = 0; v < 3; ++v)
          a = fmaf(P[icc][2 * a0 + u][2 * b0 + v], wa[icc * 9 + u * 3 + v], a);
    y1[ch][pos] = fmaxf(a, 0.f);
  }
  __syncthreads();
  if (t < 16) {
    float a = sp_bb[i * 16 + t];
    const float* wb = sp_wb + (size_t)(i * 16 + t) * 16 * 9;
    for (int ch = 0; ch < 16; ++ch)
#pragma unroll
      for (int pos = 0; pos < 9; ++pos)
        a = fmaf(y1[ch][pos], wb[ch * 9 + pos], a);
    y2[t] = fmaxf(a, 0.f);
  }
  __syncthreads();
  if (t < 16) {
    float a = sp_sb[i * 16 + t];
    const float* swp = sp_sw + (size_t)(i * 16 + t) * 16;
    for (int ch = 0; ch < 16; ++ch) a = fmaf(y2[ch], swp[ch], a);
    sp_sd[((size_t)i * 64 + b) * 16 + t] = a;
  }
}

// ---------------- final fuse -----------------------------------------------
__global__ __launch_bounds__(256) void fuse_kernel(
    const float* __restrict__ f_all, const float* __restrict__ sp_sd,
    const float* __restrict__ so_w, const float* __restrict__ so_b,
    const float* __restrict__ fp, float* __restrict__ out) {
  int g = blockIdx.x * 256 + threadIdx.x;
  if (g >= 1024) return;
  int b = g >> 4, o = g & 15;
  float tot = 0.f;
  for (int i = 0; i < 5; ++i) {
    float s = so_b[i * 16 + o];
    for (int c = 0; c < 16; ++c)
      s += f_all[(((size_t)i * 64 + b) * 16 + c) * 121 + 60] *
           so_w[(i * 16 + o) * 16 + c];
    tot += fp[i] * s;
    tot += fp[5 + i] * sp_sd[((size_t)i * 64 + b) * 16 + o];
  }
  out[g] = tot;
}

extern "C" void kernel_launch(void* const* d_in, const int* in_sizes, int n_in,
                              void* d_out, int out_size, void* d_ws,
                              size_t ws_size, hipStream_t stream) {
  const float* x = (const float*)d_in[0];
  const float* w3d1 = (const float*)d_in[1];
  const float* b3d1 = (const float*)d_in[2];
  const float* w3d23 = (const float*)d_in[3];
  const float* b3d23 = (const float*)d_in[4];
  const float* cpr_w = (const float*)d_in[5];
  const float* w2d45 = (const float*)d_in[6];
  const float* b2d45 = (const float*)d_in[7];
  const float* seg_w = (const float*)d_in[8];
  const float* seg_b = (const float*)d_in[9];
  const float* so_w = (const float*)d_in[10];
  const float* so_b = (const float*)d_in[11];
  const float* sp_wa = (const float*)d_in[12];
  const float* sp_ba = (const float*)d_in[13];
  const float* sp_wb = (const float*)d_in[14];
  const float* sp_bb = (const float*)d_in[15];
  const float* sp_sw = (const float*)d_in[16];
  const float* sp_sb = (const float*)d_in[17];
  const float* fpar = (const float*)d_in[18];

  float* ws = (float*)d_ws;
  float* x_t = ws;                       // 991232 f
  float* a_sm = x_t + 991232;            // 6144 f
  float* f_all = a_sm + 6144;            // 619520 f
  float* sp_sd = f_all + 619520;         // 5120 f
  float* wrep1 = sp_sd + 5120;           // 1008 f (+pad)
  unsigned int* pk1 = (unsigned int*)(wrep1 + 1024);  // PK_ELEMS u32
  unsigned int* pk2 = pk1 + PK_ELEMS;                 // PK_ELEMS u32
  unsigned short* arep = (unsigned short*)(pk2 + PK_ELEMS);  // 65536 u16

  transpose_kernel<<<64, 256, 0, stream>>>(x, x_t);
  softmax_kernel<<<48, 128, 0, stream>>>(cpr_w, a_sm);
  repack1_kernel<<<4, 256, 0, stream>>>(w3d1, wrep1);
  arep_kernel<<<256, 256, 0, stream>>>(w3d23, arep);

  conv1_kernel<<<dim3(33, 64), 256, 0, stream>>>(x_t, wrep1, b3d1, a_sm, pk1,
                                                 f_all);
  conv_mfma_kernel<true><<<dim3(6, 64), 512, 0, stream>>>(
      pk1, arep, b3d23, a_sm + 2048, pk2, f_all + F_SLICE);
  conv_mfma_kernel<false><<<dim3(6, 64), 512, 0, stream>>>(
      pk2, arep + 32768, b3d23 + 16, a_sm + 4096, nullptr,
      f_all + 2 * F_SLICE);

  conv2d2_kernel<<<64, 128, 0, stream>>>(f_all + 2 * F_SLICE, w2d45, b2d45,
                                         f_all + 3 * F_SLICE,
                                         f_all + 4 * F_SLICE);

  sp_prep_kernel<<<dim3(64, 5), 128, 0, stream>>>(
      f_all, x_t, seg_w, seg_b, sp_wa, sp_ba, sp_wb, sp_bb, sp_sw, sp_sb,
      sp_sd);
  fuse_kernel<<<4, 256, 0, stream>>>(f_all, sp_sd, so_w, so_b, fpar,
                                     (float*)d_out);
}

// Round 6
// 1272.286 us; speedup vs baseline: 1.0909x; 1.0909x over previous
//
#include <hip/hip_runtime.h>
#include <hip/hip_bf16.h>

// ---------------------------------------------------------------------------
// Segment_3DCenter round 6: identical structure to round 4/5, but
// conv_mfma __launch_bounds__(512, 2): round 5's (512,4) made the backend
// allocate only 64 VGPRs -> massive scratch spills (WRITE_SIZE 352 MB on a
// kernel that writes ~70 MB; FETCH 815 MB). (512,2) gives the allocator a
// 256-VGPR cap; LDS (74.75 KB) still limits to 2 blocks/CU = 16 waves/CU.
// pk layout: pk[b][p][rawd 134][ic 16] u32 ({hi,lo} f16 pair, x256 scale).
// ---------------------------------------------------------------------------

#define F_SLICE (64 * 16 * 121)  // 123904
#define PK_ELEMS (64 * 121 * 134 * 16)
#define PSTR 18672  // LDS part stride (halves): 52*352 + guard 368

typedef _Float16 half8 __attribute__((ext_vector_type(8)));
typedef float float4v __attribute__((ext_vector_type(4)));

union HU { _Float16 h; unsigned short u; };

__device__ inline unsigned pack_pair(float sv) {
  float s = sv * 256.f;
  _Float16 hi = (_Float16)s;
  _Float16 lo = (_Float16)(s - (float)hi);
  HU a, c; a.h = hi; c.h = lo;
  return (unsigned)a.u | ((unsigned)c.u << 16);
}

// ---------------- transpose x: [b][c][p] -> [b][p][c], LDS-tiled -----------
__global__ __launch_bounds__(256) void transpose_kernel(
    const float* __restrict__ x, float* __restrict__ x_t) {
  __shared__ float tile[128][123];
  int b = blockIdx.x, t = threadIdx.x;
  const float* xb = x + (size_t)b * 128 * 121;
  for (int idx = t; idx < 128 * 121; idx += 256) {
    int c = idx / 121, p = idx - c * 121;
    tile[c][p] = xb[idx];
  }
  __syncthreads();
  float* ob = x_t + (size_t)b * 121 * 128;
  for (int idx = t; idx < 121 * 128; idx += 256) {
    int p = idx >> 7, c = idx & 127;
    ob[idx] = tile[c][p];
  }
}

// ---------------- softmax over last dim of cpr_w (48 rows x 128) -----------
__global__ __launch_bounds__(128) void softmax_kernel(
    const float* __restrict__ w, float* __restrict__ a) {
  int row = blockIdx.x, t = threadIdx.x;
  __shared__ float red[128];
  float v = w[row * 128 + t];
  red[t] = v;
  __syncthreads();
  for (int s = 64; s; s >>= 1) {
    if (t < s) red[t] = fmaxf(red[t], red[t + s]);
    __syncthreads();
  }
  float m = red[0];
  __syncthreads();
  float e = expf(v - m);
  red[t] = e;
  __syncthreads();
  for (int s = 64; s; s >>= 1) {
    if (t < s) red[t] += red[t + s];
    __syncthreads();
  }
  a[row * 128 + t] = e / red[0];
}

// ---------------- repack conv1 weights (fp32 path) -------------------------
__global__ __launch_bounds__(256) void repack1_kernel(
    const float* __restrict__ w3d1, float* __restrict__ wrep1) {
  int r = blockIdx.x * 256 + threadIdx.x;
  if (r < 1008) {
    int j = r;
    int kw = j % 3; j /= 3;
    int o = j % 8; j /= 8;
    int kh = j % 3; j /= 3;
    int kd = j % 7; j /= 7;
    int gg = j;
    wrep1[r] = w3d1[(gg * 8 + o) * 63 + kd * 9 + kh * 3 + kw];
  }
}

// ---------------- repack conv2/3 weights into MFMA A-frag layout -----------
// arep[cv 2][chunk 32][part 2][lane 64][j 8] f16, scaled x256.
__global__ __launch_bounds__(256) void arep_kernel(
    const float* __restrict__ w3d23, unsigned short* __restrict__ arep) {
  int idx = blockIdx.x * 256 + threadIdx.x;  // 0..65535
  int j = idx & 7;
  int lane = (idx >> 3) & 63;
  int part = (idx >> 9) & 1;
  int chunk = (idx >> 10) & 31;
  int cv = idx >> 15;
  int m = lane & 15, qq = lane >> 4;
  int e = chunk * 2 + (qq >> 1);
  int ic = (qq & 1) * 8 + j;
  float w = 0.f;
  if (e < 63) {
    int kd = e / 9, kh = (e % 9) / 3, kw = e % 3;
    w = w3d23[((cv * 16 + m) * 16 + ic) * 63 + kd * 9 + kh * 3 + kw] * 256.f;
  }
  _Float16 hi = (_Float16)w;
  HU out;
  out.h = (part == 0) ? hi : (_Float16)(w - (float)hi);
  arep[idx] = out.u;
}

// ---------------- conv1 (ic=1) fp32: x_t -> pk1 (+fused cpr f1, d-halo) ----
__global__ __launch_bounds__(256, 4) void conv1_kernel(
    const float* __restrict__ in, const float* __restrict__ wrep,
    const float* __restrict__ bias, const float* __restrict__ al,
    unsigned int* __restrict__ pkout, float* __restrict__ f_out) {
  __shared__ float in_lds[18][134];
  __shared__ float red[2][16][4];
  const int t = threadIdx.x;
  const int bx = blockIdx.x;
  const int b = blockIdx.y;
  const int h = bx / 3;
  const int w0 = (bx % 3) * 4;
  const int lane = t & 63;
  const int wv = t >> 6;
  const int dh = wv & 1;
  const int dd = lane + (dh << 6);
  const int g = __builtin_amdgcn_readfirstlane(wv >> 1);
  const int oc_base = g << 3;

  float acc[8][4];
#pragma unroll
  for (int o = 0; o < 8; ++o)
#pragma unroll
    for (int c = 0; c < 4; ++c) acc[o][c] = 0.f;

  const int ds = t & 127;
  const int half = t >> 7;

  for (int r = half; r < 18; r += 2) {
    int hr = r / 6;
    int wc = r - hr * 6;
    int hh = h - 1 + hr;
    int ww = w0 - 1 + wc;
    bool ok = (hh >= 0) & (hh < 11) & (ww >= 0) & (ww < 11);
    const float* src = in + (((size_t)b) * 121 + hh * 11 + ww) * 128;
    float v = 0.f;
    if (ok && ds >= 3) v = src[ds - 3];
    in_lds[r][ds] = v;
    if (ds < 6) {
      float v2 = 0.f;
      if (ok && ds < 3) v2 = src[125 + ds];
      in_lds[r][128 + ds] = v2;
    }
  }
  __syncthreads();
  const float* wbase = wrep + g * 504;
#pragma unroll
  for (int kd = 0; kd < 7; ++kd) {
#pragma unroll
    for (int kh = 0; kh < 3; ++kh) {
      float ws[24];
      const float* wp = wbase + kd * 72 + kh * 24;
#pragma unroll
      for (int j = 0; j < 24; ++j) ws[j] = wp[j];
      float v[6];
#pragma unroll
      for (int qq = 0; qq < 6; ++qq) v[qq] = in_lds[kh * 6 + qq][dd + kd];
#pragma unroll
      for (int o = 0; o < 8; ++o)
#pragma unroll
        for (int kw = 0; kw < 3; ++kw) {
          float wv_ = ws[o * 3 + kw];
#pragma unroll
          for (int c = 0; c < 4; ++c)
            acc[o][c] = fmaf(wv_, v[kw + c], acc[o][c]);
        }
    }
  }

  const int p0 = h * 11 + w0;
  float alv[8];
#pragma unroll
  for (int o = 0; o < 8; ++o) alv[o] = al[(oc_base + o) * 128 + dd];
#pragma unroll
  for (int o = 0; o < 8; ++o) {
    float bv = bias[oc_base + o];
#pragma unroll
    for (int c = 0; c < 4; ++c) {
      float sv = fmaxf(acc[o][c] + bv, 0.f);
      if (w0 + c < 11)
        pkout[(((size_t)b * 121 + p0 + c) * 134 + dd + 3) * 16 + oc_base + o] =
            pack_pair(sv);
      float pv = sv * alv[o];
#pragma unroll
      for (int off = 32; off; off >>= 1) pv += __shfl_down(pv, off, 64);
      if (lane == 0) red[dh][oc_base + o][c] = pv;
    }
  }
  // fused d-halo zeroing (replaces zeropad kernel for pk1)
  if (dd < 3) {
#pragma unroll
    for (int c = 0; c < 4; ++c) {
      if (w0 + c < 11) {
        size_t b0 = (((size_t)b * 121 + p0 + c) * 134 + dd) * 16 + oc_base;
        size_t b1 = (((size_t)b * 121 + p0 + c) * 134 + 131 + dd) * 16 + oc_base;
#pragma unroll
        for (int o = 0; o < 8; ++o) { pkout[b0 + o] = 0u; pkout[b1 + o] = 0u; }
      }
    }
  }
  __syncthreads();
  if (t < 64) {
    int oc = t >> 2, c = t & 3;
    if (w0 + c < 11)
      f_out[((size_t)b * 16 + oc) * 121 + p0 + c] =
          fmaxf(red[0][oc][c] + red[1][oc][c], 0.f);
  }
}

// ---------------- conv2/conv3: MFMA f16x2-split, h-pair blocks -------------
// Block = (h-pair bx, b), 512 thr = 8 waves: hs = wave>>2 (h sub-row),
// wg = wave&3 (w-triple). Stages 4 rows x 13 cols x 22 d x 16 ic per d16.
// LDS: lds2[part 2][panel 52][ich 2][d 22][ic8] halves, part stride PSTR
// (incl. guard for dummy-pixel reads).
template <bool WRITE_PK>
__global__ __launch_bounds__(512, 2) void conv_mfma_kernel(
    const unsigned int* __restrict__ pkin,
    const unsigned short* __restrict__ arep, const float* __restrict__ bias,
    const float* __restrict__ al, unsigned int* __restrict__ pkout,
    float* __restrict__ f_out) {
  __shared__ _Float16 lds2[2][PSTR];
  const int t = threadIdx.x;
  const int bx = blockIdx.x, b = blockIdx.y;
  const int lane = t & 63, wave = t >> 6;
  const int n = lane & 15, q = lane >> 4;
  const int hs = wave >> 2, wg = wave & 3;
  const int h = 2 * bx + hs;  // 0..11 (11 = dummy)

  // staging descriptors: 4576 uint4-units = 52 panels x 22 d x 4 ic-quads
  int gbase[9], lbase[9];
#pragma unroll
  for (int i = 0; i < 9; ++i) {
    int u = t + i * 512;
    if (u < 4576) {
      int q4 = u & 3;
      int rem = u >> 2;
      int panel = rem / 22;
      int dloc = rem - panel * 22;
      int rr = panel / 13, cc = panel - rr * 13;
      int hh = 2 * bx + rr - 1, ww = cc - 1;
      bool ok = (hh >= 0) & (hh < 11) & (ww >= 0) & (ww < 11);
      lbase[i] = panel * 352 + (q4 >> 1) * 176 + dloc * 8 + (q4 & 1) * 4;
      gbase[i] = ok ? (((b * 121 + hh * 11 + ww) * 134 + dloc) * 16 + q4 * 4)
                    : -1;
    } else {
      lbase[i] = -1;
      gbase[i] = -1;
    }
  }
  // zero invalid units once; valid units overwritten every d16
#pragma unroll
  for (int i = 0; i < 9; ++i) {
    if (lbase[i] >= 0 && gbase[i] < 0) {
      uint2 z; z.x = 0u; z.y = 0u;
      *(uint2*)&lds2[0][lbase[i]] = z;
      *(uint2*)&lds2[1][lbase[i]] = z;
    }
  }

  float bias_r[4];
#pragma unroll
  for (int r = 0; r < 4; ++r) bias_r[r] = bias[q * 4 + r];

  const int bbase = (q & 1) * 176 + n * 8;
  float facc[3][4];
#pragma unroll
  for (int tt = 0; tt < 3; ++tt)
#pragma unroll
    for (int r = 0; r < 4; ++r) facc[tt][r] = 0.f;

  for (int d16 = 0; d16 < 8; ++d16) {
    __syncthreads();
#pragma unroll
    for (int i = 0; i < 9; ++i) {
      if (gbase[i] >= 0) {
        uint4 v = *(const uint4*)&pkin[gbase[i] + d16 * 256];
        uint2 hv, lv;
        hv.x = (v.x & 0xffffu) | (v.y << 16);
        hv.y = (v.z & 0xffffu) | (v.w << 16);
        lv.x = (v.x >> 16) | (v.y & 0xffff0000u);
        lv.y = (v.z >> 16) | (v.w & 0xffff0000u);
        *(uint2*)&lds2[0][lbase[i]] = hv;
        *(uint2*)&lds2[1][lbase[i]] = lv;
      }
    }
    // hoisted al loads for this d16 (consumed in epilogue)
    float alr[4];
#pragma unroll
    for (int r = 0; r < 4; ++r) alr[r] = al[(q * 4 + r) * 128 + d16 * 16 + n];
    __syncthreads();

    float4v acc[3];
#pragma unroll
    for (int tt = 0; tt < 3; ++tt) acc[tt] = (float4v){0.f, 0.f, 0.f, 0.f};

#pragma unroll
    for (int c = 0; c < 32; ++c) {
      const int e0 = 2 * c, e1r = 2 * c + 1;
      const int e0c = (e0 > 62) ? 62 : e0;
      const int e1 = (e1r > 62) ? 62 : e1r;
      const int sel0 =
          ((hs + (e0c % 9) / 3) * 13 + (e0c % 3)) * 352 + (e0c / 9) * 8;
      const int sel1 =
          ((hs + (e1 % 9) / 3) * 13 + (e1 % 3)) * 352 + (e1 / 9) * 8;
      const int sel = (lane & 32) ? sel1 : sel0;
      half8 ahi = *(const half8*)&arep[((c * 2 + 0) * 64 + lane) * 8];
      half8 alo = *(const half8*)&arep[((c * 2 + 1) * 64 + lane) * 8];
#pragma unroll
      for (int tt = 0; tt < 3; ++tt) {
        const int wl = wg * 3 + tt;  // 0..11 (11 dummy)
        const _Float16* ph = &lds2[0][bbase + sel + wl * 352];
        half8 bhi = *(const half8*)ph;
        half8 blo = *(const half8*)(ph + PSTR);
        acc[tt] = __builtin_amdgcn_mfma_f32_16x16x32_f16(ahi, bhi, acc[tt], 0, 0, 0);
        acc[tt] = __builtin_amdgcn_mfma_f32_16x16x32_f16(ahi, blo, acc[tt], 0, 0, 0);
        acc[tt] = __builtin_amdgcn_mfma_f32_16x16x32_f16(alo, bhi, acc[tt], 0, 0, 0);
      }
    }

    // epilogue for this d16
#pragma unroll
    for (int tt = 0; tt < 3; ++tt) {
      const int wl = wg * 3 + tt;
      if (h < 11 && wl < 11) {
        const int p = h * 11 + wl;
        unsigned pkarr[4];
#pragma unroll
        for (int r = 0; r < 4; ++r) {
          float sv = fmaxf(acc[tt][r] * (1.f / 65536.f) + bias_r[r], 0.f);
          if (WRITE_PK) pkarr[r] = pack_pair(sv);
          facc[tt][r] += sv * alr[r];
        }
        if (WRITE_PK) {
          uint4 pkv;
          pkv.x = pkarr[0]; pkv.y = pkarr[1]; pkv.z = pkarr[2]; pkv.w = pkarr[3];
          *(uint4*)&pkout[(((size_t)b * 121 + p) * 134 + d16 * 16 + n + 3) * 16 +
                          q * 4] = pkv;
          // fused d-halo zeroing for pk2
          if (d16 == 0 && n < 3) {
            uint4 z = {0u, 0u, 0u, 0u};
            *(uint4*)&pkout[(((size_t)b * 121 + p) * 134 + n) * 16 + q * 4] = z;
          }
          if (d16 == 7 && n >= 13) {
            uint4 z = {0u, 0u, 0u, 0u};
            *(uint4*)&pkout[(((size_t)b * 121 + p) * 134 + n + 118) * 16 +
                            q * 4] = z;
          }
        }
      }
    }
  }

  // fused cpr: reduce facc over the 16 n-lanes of each quad-group
#pragma unroll
  for (int tt = 0; tt < 3; ++tt) {
    const int wl = wg * 3 + tt;
#pragma unroll
    for (int r = 0; r < 4; ++r) {
      float v = facc[tt][r];
      v += __shfl_xor(v, 1, 64);
      v += __shfl_xor(v, 2, 64);
      v += __shfl_xor(v, 4, 64);
      v += __shfl_xor(v, 8, 64);
      if (n == 0 && h < 11 && wl < 11)
        f_out[((size_t)b * 16 + q * 4 + r) * 121 + h * 11 + wl] =
            fmaxf(v, 0.f);
    }
  }
}

// ---------------- both 16->16 2D convs (3x3 pad1 + relu), fused ------------
__global__ __launch_bounds__(128) void conv2d2_kernel(
    const float* __restrict__ fin, const float* __restrict__ wgt,
    const float* __restrict__ bias, float* __restrict__ f4,
    float* __restrict__ f5) {
  const int b = blockIdx.x, t = threadIdx.x;
  __shared__ float buf0[16 * 121];
  __shared__ float buf1[16 * 121];
  const float* fb = fin + (size_t)b * 16 * 121;
  for (int idx = t; idx < 16 * 121; idx += 128) buf0[idx] = fb[idx];
  __syncthreads();
  for (int layer = 0; layer < 2; ++layer) {
    const float* src = layer ? buf1 : buf0;
    float* dst = layer ? nullptr : buf1;
    const float* wl = wgt + layer * 2304;
    const float* bl = bias + layer * 16;
    float* go = (layer ? f5 : f4) + (size_t)b * 16 * 121;
    if (t < 121) {
      int h = t / 11, w = t - h * 11;
      float acc[16];
#pragma unroll
      for (int o = 0; o < 16; ++o) acc[o] = bl[o];
      for (int ic = 0; ic < 16; ++ic) {
#pragma unroll
        for (int u = 0; u < 3; ++u) {
          int hh = h + u - 1;
#pragma unroll
          for (int v = 0; v < 3; ++v) {
            int ww = w + v - 1;
            float val = (hh >= 0 && hh < 11 && ww >= 0 && ww < 11)
                            ? src[ic * 121 + hh * 11 + ww]
                            : 0.f;
            const float* wp = wl + ic * 9 + u * 3 + v;
#pragma unroll
            for (int o = 0; o < 16; ++o)
              acc[o] = fmaf(val, wp[o * 144], acc[o]);
          }
        }
      }
#pragma unroll
      for (int o = 0; o < 16; ++o) {
        float r = fmaxf(acc[o], 0.f);
        go[o * 121 + t] = r;
        if (dst) dst[o * 121 + t] = r;
      }
    }
    __syncthreads();
  }
}

// ---------------- sp path: seg conv -> top5 -> patch convs -> side ---------
__global__ __launch_bounds__(128) void sp_prep_kernel(
    const float* __restrict__ f_all, const float* __restrict__ x_t,
    const float* __restrict__ seg_w, const float* __restrict__ seg_b,
    const float* __restrict__ sp_wa, const float* __restrict__ sp_ba,
    const float* __restrict__ sp_wb, const float* __restrict__ sp_bb,
    const float* __restrict__ sp_sw, const float* __restrict__ sp_sb,
    float* __restrict__ sp_sd) {
  const int b = blockIdx.x, i = blockIdx.y;
  const int t = threadIdx.x;
  __shared__ float fl[16 * 121];
  __shared__ float act[121];
  __shared__ float diffs[121];
  __shared__ int sel[5];
  __shared__ float s7[7], xc7[7];
  __shared__ float P[2][7][7];
  __shared__ float y1[16][9];
  __shared__ float y2[16];

  const float* fb = f_all + ((size_t)i * 64 + b) * 16 * 121;
  for (int idx = t; idx < 16 * 121; idx += 128) fl[idx] = fb[idx];
  __syncthreads();

  if (t < 121) {
    int h = t / 11, w = t - h * 11;
    float a = seg_b[i];
    const float* sw = seg_w + i * 144;
#pragma unroll
    for (int u = 0; u < 3; ++u) {
      int hh = h + u - 1;
#pragma unroll
      for (int v = 0; v < 3; ++v) {
        int ww = w + v - 1;
        if (hh >= 0 && hh < 11 && ww >= 0 && ww < 11) {
          int pp = hh * 11 + ww;
          for (int ic = 0; ic < 16; ++ic)
            a = fmaf(fl[ic * 121 + pp], sw[ic * 9 + u * 3 + v], a);
        }
      }
    }
    act[t] = a;
  }
  __syncthreads();
  if (t < 121) diffs[t] = fabsf(act[t] - act[60]);
  __syncthreads();

  for (int k = 0; k < 5; ++k) {
    if (t < 64) {
      float d0 = diffs[t];
      int i0 = t;
      float d1 = (t + 64 < 121) ? diffs[t + 64] : 3.0e38f;
      if (d1 < d0) { d0 = d1; i0 = t + 64; }
#pragma unroll
      for (int off = 32; off; off >>= 1) {
        float od = __shfl_down(d0, off, 64);
        int oi = __shfl_down(i0, off, 64);
        if (od < d0 || (od == d0 && oi < i0)) { d0 = od; i0 = oi; }
      }
      if (t == 0) {
        sel[k] = i0;
        diffs[i0] = 3.0e38f;
      }
    }
    __syncthreads();
  }

  if (t < 7) {
    const float* xb = x_t + (size_t)b * 121 * 128;
    float s = 0.f;
    for (int k = 0; k < 5; ++k) s += xb[(size_t)sel[k] * 128 + 61 + t];
    s7[t] = s;
    xc7[t] = xb[60 * 128 + 61 + t];
  }
  __syncthreads();
  if (t < 49) {
    int r = t / 7, c = t - r * 7;
    float d0 = s7[c];
    if (fabsf(d0) < 0.01f) d0 = 0.01f;
    float d1 = xc7[c];
    if (fabsf(d1) < 0.01f) d1 = 0.01f;
    P[0][r][c] = s7[r] / d0;
    P[1][r][c] = xc7[r] / d1;
  }
  __syncthreads();
  for (int item = t; item < 144; item += 128) {
    int ch = item / 9, pos = item - ch * 9;
    int a0 = pos / 3, b0 = pos - a0 * 3;
    float a = sp_ba[i * 16 + ch];
    const float* wa = sp_wa + ((size_t)(i * 16 + ch) * 2) * 9;
#pragma unroll
    for (int icc = 0; icc < 2; ++icc)
#pragma unroll
      for (int u = 0; u < 3; ++u)
#pragma unroll
        for (int v = 0; v < 3; ++v)
          a = fmaf(P[icc][2 * a0 + u][2 * b0 + v], wa[icc * 9 + u * 3 + v], a);
    y1[ch][pos] = fmaxf(a, 0.f);
  }
  __syncthreads();
  if (t < 16) {
    float a = sp_bb[i * 16 + t];
    const float* wb = sp_wb + (size_t)(i * 16 + t) * 16 * 9;
    for (int ch = 0; ch < 16; ++ch)
#pragma unroll
      for (int pos = 0; pos < 9; ++pos)
        a = fmaf(y1[ch][pos], wb[ch * 9 + pos], a);
    y2[t] = fmaxf(a, 0.f);
  }
  __syncthreads();
  if (t < 16) {
    float a = sp_sb[i * 16 + t];
    const float* swp = sp_sw + (size_t)(i * 16 + t) * 16;
    for (int ch = 0; ch < 16; ++ch) a = fmaf(y2[ch], swp[ch], a);
    sp_sd[((size_t)i * 64 + b) * 16 + t] = a;
  }
}

// ---------------- final fuse -----------------------------------------------
__global__ __launch_bounds__(256) void fuse_kernel(
    const float* __restrict__ f_all, const float* __restrict__ sp_sd,
    const float* __restrict__ so_w, const float* __restrict__ so_b,
    const float* __restrict__ fp, float* __restrict__ out) {
  int g = blockIdx.x * 256 + threadIdx.x;
  if (g >= 1024) return;
  int b = g >> 4, o = g & 15;
  float tot = 0.f;
  for (int i = 0; i < 5; ++i) {
    float s = so_b[i * 16 + o];
    for (int c = 0; c < 16; ++c)
      s += f_all[(((size_t)i * 64 + b) * 16 + c) * 121 + 60] *
           so_w[(i * 16 + o) * 16 + c];
    tot += fp[i] * s;
    tot += fp[5 + i] * sp_sd[((size_t)i * 64 + b) * 16 + o];
  }
  out[g] = tot;
}

extern "C" void kernel_launch(void* const* d_in, const int* in_sizes, int n_in,
                              void* d_out, int out_size, void* d_ws,
                              size_t ws_size, hipStream_t stream) {
  const float* x = (const float*)d_in[0];
  const float* w3d1 = (const float*)d_in[1];
  const float* b3d1 = (const float*)d_in[2];
  const float* w3d23 = (const float*)d_in[3];
  const float* b3d23 = (const float*)d_in[4];
  const float* cpr_w = (const float*)d_in[5];
  const float* w2d45 = (const float*)d_in[6];
  const float* b2d45 = (const float*)d_in[7];
  const float* seg_w = (const float*)d_in[8];
  const float* seg_b = (const float*)d_in[9];
  const float* so_w = (const float*)d_in[10];
  const float* so_b = (const float*)d_in[11];
  const float* sp_wa = (const float*)d_in[12];
  const float* sp_ba = (const float*)d_in[13];
  const float* sp_wb = (const float*)d_in[14];
  const float* sp_bb = (const float*)d_in[15];
  const float* sp_sw = (const float*)d_in[16];
  const float* sp_sb = (const float*)d_in[17];
  const float* fpar = (const float*)d_in[18];

  float* ws = (float*)d_ws;
  float* x_t = ws;                       // 991232 f
  float* a_sm = x_t + 991232;            // 6144 f
  float* f_all = a_sm + 6144;            // 619520 f
  float* sp_sd = f_all + 619520;         // 5120 f
  float* wrep1 = sp_sd + 5120;           // 1008 f (+pad)
  unsigned int* pk1 = (unsigned int*)(wrep1 + 1024);  // PK_ELEMS u32
  unsigned int* pk2 = pk1 + PK_ELEMS;                 // PK_ELEMS u32
  unsigned short* arep = (unsigned short*)(pk2 + PK_ELEMS);  // 65536 u16

  transpose_kernel<<<64, 256, 0, stream>>>(x, x_t);
  softmax_kernel<<<48, 128, 0, stream>>>(cpr_w, a_sm);
  repack1_kernel<<<4, 256, 0, stream>>>(w3d1, wrep1);
  arep_kernel<<<256, 256, 0, stream>>>(w3d23, arep);

  conv1_kernel<<<dim3(33, 64), 256, 0, stream>>>(x_t, wrep1, b3d1, a_sm, pk1,
                                                 f_all);
  conv_mfma_kernel<true><<<dim3(6, 64), 512, 0, stream>>>(
      pk1, arep, b3d23, a_sm + 2048, pk2, f_all + F_SLICE);
  conv_mfma_kernel<false><<<dim3(6, 64), 512, 0, stream>>>(
      pk2, arep + 32768, b3d23 + 16, a_sm + 4096, nullptr,
      f_all + 2 * F_SLICE);

  conv2d2_kernel<<<64, 128, 0, stream>>>(f_all + 2 * F_SLICE, w2d45, b2d45,
                                         f_all + 3 * F_SLICE,
                                         f_all + 4 * F_SLICE);

  sp_prep_kernel<<<dim3(64, 5), 128, 0, stream>>>(
      f_all, x_t, seg_w, seg_b, sp_wa, sp_ba, sp_wb, sp_bb, sp_sw, sp_sb,
      sp_sd);
  fuse_kernel<<<4, 256, 0, stream>>>(f_all, sp_sd, so_w, so_b, fpar,
                                     (float*)d_out);
}

// Round 7
// 506.397 us; speedup vs baseline: 2.7408x; 2.5124x over previous
//
#include <hip/hip_runtime.h>
#include <hip/hip_bf16.h>

// ---------------------------------------------------------------------------
// Segment_3DCenter round 7: conv2/conv3 MFMA f16 hi/lo split, flattened grid.
// Grid = (h-pair 6, d16 8, b 64) = 3072 blocks x 512 thr; each block does ONE
// staging pass + ONE compute pass (phase overlap via co-resident blocks).
// pk stored as separate hi/lo u16 planes: pk[b][p][rawd 134][ic 16] (x256
// scale); staging is a pure 16B->LDS copy with affine layout addr=unit*16B.
// cpr partial sums accumulated with atomicAdd into zeroed f_all; consumers
// apply relu on load (exact: all feats are relu outputs).
// ---------------------------------------------------------------------------

#define F_SLICE (64 * 16 * 121)          // 123904
#define PKE (64 * 121 * 134 * 16)        // u16 elements per pk plane
#define LHALF 18304                      // LDS halves per part (52*352)

typedef _Float16 half8 __attribute__((ext_vector_type(8)));
typedef float float4v __attribute__((ext_vector_type(4)));
typedef unsigned short u16x8 __attribute__((ext_vector_type(8)));
typedef unsigned short u16x4 __attribute__((ext_vector_type(4)));

union HU { _Float16 h; unsigned short u; };

// ---------------- transpose x: [b][c][p] -> [b][p][c], LDS-tiled -----------
__global__ __launch_bounds__(256) void transpose_kernel(
    const float* __restrict__ x, float* __restrict__ x_t) {
  __shared__ float tile[128][123];
  int b = blockIdx.x, t = threadIdx.x;
  const float* xb = x + (size_t)b * 128 * 121;
  for (int idx = t; idx < 128 * 121; idx += 256) {
    int c = idx / 121, p = idx - c * 121;
    tile[c][p] = xb[idx];
  }
  __syncthreads();
  float* ob = x_t + (size_t)b * 121 * 128;
  for (int idx = t; idx < 121 * 128; idx += 256) {
    int p = idx >> 7, c = idx & 127;
    ob[idx] = tile[c][p];
  }
}

// ---------------- softmax over last dim of cpr_w (48 rows x 128) -----------
__global__ __launch_bounds__(128) void softmax_kernel(
    const float* __restrict__ w, float* __restrict__ a) {
  int row = blockIdx.x, t = threadIdx.x;
  __shared__ float red[128];
  float v = w[row * 128 + t];
  red[t] = v;
  __syncthreads();
  for (int s = 64; s; s >>= 1) {
    if (t < s) red[t] = fmaxf(red[t], red[t + s]);
    __syncthreads();
  }
  float m = red[0];
  __syncthreads();
  float e = expf(v - m);
  red[t] = e;
  __syncthreads();
  for (int s = 64; s; s >>= 1) {
    if (t < s) red[t] += red[t + s];
    __syncthreads();
  }
  a[row * 128 + t] = e / red[0];
}

// ---------------- zero f_all slices 1,2 (atomic accumulation targets) ------
__global__ __launch_bounds__(256) void zerof_kernel(float* __restrict__ p) {
  int i = blockIdx.x * 256 + threadIdx.x;
  if (i < 2 * F_SLICE) p[i] = 0.f;
}

// ---------------- repack conv1 weights (fp32 path) -------------------------
__global__ __launch_bounds__(256) void repack1_kernel(
    const float* __restrict__ w3d1, float* __restrict__ wrep1) {
  int r = blockIdx.x * 256 + threadIdx.x;
  if (r < 1008) {
    int j = r;
    int kw = j % 3; j /= 3;
    int o = j % 8; j /= 8;
    int kh = j % 3; j /= 3;
    int kd = j % 7; j /= 7;
    int gg = j;
    wrep1[r] = w3d1[(gg * 8 + o) * 63 + kd * 9 + kh * 3 + kw];
  }
}

// ---------------- repack conv2/3 weights into MFMA A-frag layout -----------
// arep[cv 2][chunk 32][part 2][lane 64][j 8] f16, scaled x256.
__global__ __launch_bounds__(256) void arep_kernel(
    const float* __restrict__ w3d23, unsigned short* __restrict__ arep) {
  int idx = blockIdx.x * 256 + threadIdx.x;  // 0..65535
  int j = idx & 7;
  int lane = (idx >> 3) & 63;
  int part = (idx >> 9) & 1;
  int chunk = (idx >> 10) & 31;
  int cv = idx >> 15;
  int m = lane & 15, qq = lane >> 4;
  int e = chunk * 2 + (qq >> 1);
  int ic = (qq & 1) * 8 + j;
  float w = 0.f;
  if (e < 63) {
    int kd = e / 9, kh = (e % 9) / 3, kw = e % 3;
    w = w3d23[((cv * 16 + m) * 16 + ic) * 63 + kd * 9 + kh * 3 + kw] * 256.f;
  }
  _Float16 hi = (_Float16)w;
  HU out;
  out.h = (part == 0) ? hi : (_Float16)(w - (float)hi);
  arep[idx] = out.u;
}

// ---------------- conv1 (ic=1) fp32: x_t -> pk1 planes (+fused cpr f1) -----
__global__ __launch_bounds__(256, 4) void conv1_kernel(
    const float* __restrict__ in, const float* __restrict__ wrep,
    const float* __restrict__ bias, const float* __restrict__ al,
    unsigned short* __restrict__ pk_hi, unsigned short* __restrict__ pk_lo,
    float* __restrict__ f_out) {
  __shared__ float in_lds[18][134];
  __shared__ float red[2][16][4];
  const int t = threadIdx.x;
  const int bx = blockIdx.x;
  const int b = blockIdx.y;
  const int h = bx / 3;
  const int w0 = (bx % 3) * 4;
  const int lane = t & 63;
  const int wv = t >> 6;
  const int dh = wv & 1;
  const int dd = lane + (dh << 6);
  const int g = __builtin_amdgcn_readfirstlane(wv >> 1);
  const int oc_base = g << 3;

  float acc[8][4];
#pragma unroll
  for (int o = 0; o < 8; ++o)
#pragma unroll
    for (int c = 0; c < 4; ++c) acc[o][c] = 0.f;

  const int ds = t & 127;
  const int half = t >> 7;

  for (int r = half; r < 18; r += 2) {
    int hr = r / 6;
    int wc = r - hr * 6;
    int hh = h - 1 + hr;
    int ww = w0 - 1 + wc;
    bool ok = (hh >= 0) & (hh < 11) & (ww >= 0) & (ww < 11);
    const float* src = in + (((size_t)b) * 121 + hh * 11 + ww) * 128;
    float v = 0.f;
    if (ok && ds >= 3) v = src[ds - 3];
    in_lds[r][ds] = v;
    if (ds < 6) {
      float v2 = 0.f;
      if (ok && ds < 3) v2 = src[125 + ds];
      in_lds[r][128 + ds] = v2;
    }
  }
  __syncthreads();
  const float* wbase = wrep + g * 504;
#pragma unroll
  for (int kd = 0; kd < 7; ++kd) {
#pragma unroll
    for (int kh = 0; kh < 3; ++kh) {
      float ws[24];
      const float* wp = wbase + kd * 72 + kh * 24;
#pragma unroll
      for (int j = 0; j < 24; ++j) ws[j] = wp[j];
      float v[6];
#pragma unroll
      for (int qq = 0; qq < 6; ++qq) v[qq] = in_lds[kh * 6 + qq][dd + kd];
#pragma unroll
      for (int o = 0; o < 8; ++o)
#pragma unroll
        for (int kw = 0; kw < 3; ++kw) {
          float wv_ = ws[o * 3 + kw];
#pragma unroll
          for (int c = 0; c < 4; ++c)
            acc[o][c] = fmaf(wv_, v[kw + c], acc[o][c]);
        }
    }
  }

  const int p0 = h * 11 + w0;
  // bias + relu in place
#pragma unroll
  for (int o = 0; o < 8; ++o) {
    float bv = bias[oc_base + o];
#pragma unroll
    for (int c = 0; c < 4; ++c) acc[o][c] = fmaxf(acc[o][c] + bv, 0.f);
  }
  // pk stores: 8 oc per 16B vector, hi and lo planes
#pragma unroll
  for (int c = 0; c < 4; ++c) {
    if (w0 + c < 11) {
      u16x8 hi8, lo8;
#pragma unroll
      for (int o = 0; o < 8; ++o) {
        float s = acc[o][c] * 256.f;
        _Float16 hh = (_Float16)s;
        HU a, bb;
        a.h = hh;
        bb.h = (_Float16)(s - (float)hh);
        hi8[o] = a.u;
        lo8[o] = bb.u;
      }
      size_t base = (((size_t)b * 121 + p0 + c) * 134 + dd + 3) * 16 + oc_base;
      *(u16x8*)&pk_hi[base] = hi8;
      *(u16x8*)&pk_lo[base] = lo8;
    }
  }
  // fused d-halo zeroing
  if (dd < 3) {
    u16x8 z = {0, 0, 0, 0, 0, 0, 0, 0};
#pragma unroll
    for (int c = 0; c < 4; ++c) {
      if (w0 + c < 11) {
        size_t b0 = (((size_t)b * 121 + p0 + c) * 134 + dd) * 16 + oc_base;
        size_t b1 =
            (((size_t)b * 121 + p0 + c) * 134 + 131 + dd) * 16 + oc_base;
        *(u16x8*)&pk_hi[b0] = z;
        *(u16x8*)&pk_lo[b0] = z;
        *(u16x8*)&pk_hi[b1] = z;
        *(u16x8*)&pk_lo[b1] = z;
      }
    }
  }
  // fused cpr
  float alv[8];
#pragma unroll
  for (int o = 0; o < 8; ++o) alv[o] = al[(oc_base + o) * 128 + dd];
#pragma unroll
  for (int o = 0; o < 8; ++o) {
#pragma unroll
    for (int c = 0; c < 4; ++c) {
      float pv = acc[o][c] * alv[o];
#pragma unroll
      for (int off = 32; off; off >>= 1) pv += __shfl_down(pv, off, 64);
      if (lane == 0) red[dh][oc_base + o][c] = pv;
    }
  }
  __syncthreads();
  if (t < 64) {
    int oc = t >> 2, c = t & 3;
    if (w0 + c < 11)
      f_out[((size_t)b * 16 + oc) * 121 + p0 + c] =
          fmaxf(red[0][oc][c] + red[1][oc][c], 0.f);
  }
}

// ---------------- conv2/conv3: MFMA f16x2-split, flattened grid ------------
// Block = (bx h-pair, d16, b), 512 thr = 8 waves: hs = wave>>2, wg = wave&3.
// LDS: two part planes of 18304 halves; unit u (0..4575) at bytes u*16:
// u = part*2288 + (panel*2+icq)*22 + dloc, panel = rr*13+cc (4 rows x 13 w).
template <bool WRITE_PK>
__global__ __launch_bounds__(512, 2) void conv_mfma_kernel(
    const unsigned short* __restrict__ pin_hi,
    const unsigned short* __restrict__ pin_lo,
    const unsigned short* __restrict__ arep, const float* __restrict__ bias,
    const float* __restrict__ al, unsigned short* __restrict__ pout_hi,
    unsigned short* __restrict__ pout_lo, float* __restrict__ f_out) {
  __shared__ _Float16 lds[2 * LHALF];
  const int t = threadIdx.x;
  const int bx = blockIdx.x, d16 = blockIdx.y, b = blockIdx.z;
  const int lane = t & 63, wave = t >> 6;
  const int n = lane & 15, q = lane >> 4;
  const int hs = wave >> 2, wg = wave & 3;
  const int h = 2 * bx + hs;  // 0..11 (11 = dummy)

  // ---- staging: 4576 16-B units, pure copy (planes pre-split hi/lo) ----
#pragma unroll
  for (int i = 0; i < 9; ++i) {
    int u = t + i * 512;
    if (u < 4576) {
      int part = (u >= 2288) ? 1 : 0;
      int qq = u - part * 2288;
      int pc = qq / 22;
      int dloc = qq - pc * 22;
      int panel = pc >> 1, icq = pc & 1;
      int rr = panel / 13, cc = panel - rr * 13;
      int hh = 2 * bx + rr - 1, ww = cc - 1;
      bool ok = (hh >= 0) & (hh < 11) & (ww >= 0) & (ww < 11);
      u16x8 v = {0, 0, 0, 0, 0, 0, 0, 0};
      if (ok) {
        const unsigned short* src = part ? pin_lo : pin_hi;
        v = *(const u16x8*)&src[(((size_t)b * 121 + hh * 11 + ww) * 134 +
                                d16 * 16 + dloc) *
                                   16 +
                               icq * 8];
      }
      *(u16x8*)&lds[(size_t)u * 8] = v;
    }
  }
  float bias_r[4], alr[4];
#pragma unroll
  for (int r = 0; r < 4; ++r) {
    bias_r[r] = bias[q * 4 + r];
    alr[r] = al[(q * 4 + r) * 128 + d16 * 16 + n];
  }
  __syncthreads();

  // ---- compute ----
  const int bbase = (q & 1) * 176 + n * 8;
  const int hs4576 = hs * 4576;
  int wloff[3];
#pragma unroll
  for (int tt = 0; tt < 3; ++tt) {
    int wl = wg * 3 + tt;
    int wlc = (wl > 10) ? 10 : wl;  // clamp dummy wl=11 (result discarded)
    wloff[tt] = wlc * 352;
  }

  float4v acc[3];
#pragma unroll
  for (int tt = 0; tt < 3; ++tt) acc[tt] = (float4v){0.f, 0.f, 0.f, 0.f};

#pragma unroll
  for (int c = 0; c < 32; ++c) {
    const int e0 = (2 * c > 62) ? 62 : 2 * c;
    const int e1 = (2 * c + 1 > 62) ? 62 : 2 * c + 1;
    const int c0 =
        (((e0 % 9) / 3) * 13 + (e0 % 3)) * 352 + (e0 / 9) * 8;
    const int c1 =
        (((e1 % 9) / 3) * 13 + (e1 % 3)) * 352 + (e1 / 9) * 8;
    const int scell = (lane & 32) ? c1 : c0;
    half8 ahi = *(const half8*)&arep[((c * 2 + 0) * 64 + lane) * 8];
    half8 alo = *(const half8*)&arep[((c * 2 + 1) * 64 + lane) * 8];
#pragma unroll
    for (int tt = 0; tt < 3; ++tt) {
      const _Float16* ph = &lds[bbase + hs4576 + scell + wloff[tt]];
      half8 bhi = *(const half8*)ph;
      half8 blo = *(const half8*)(ph + LHALF);
      acc[tt] = __builtin_amdgcn_mfma_f32_16x16x32_f16(ahi, bhi, acc[tt], 0, 0, 0);
      acc[tt] = __builtin_amdgcn_mfma_f32_16x16x32_f16(ahi, blo, acc[tt], 0, 0, 0);
      acc[tt] = __builtin_amdgcn_mfma_f32_16x16x32_f16(alo, bhi, acc[tt], 0, 0, 0);
    }
  }

  // ---- epilogue ----
#pragma unroll
  for (int tt = 0; tt < 3; ++tt) {
    const int wl = wg * 3 + tt;
    if (h < 11 && wl < 11) {
      const int p = h * 11 + wl;
      float fr[4];
      u16x4 hi4, lo4;
#pragma unroll
      for (int r = 0; r < 4; ++r) {
        float sv = fmaxf(acc[tt][r] * (1.f / 65536.f) + bias_r[r], 0.f);
        fr[r] = sv * alr[r];
        if (WRITE_PK) {
          float s = sv * 256.f;
          _Float16 hh = (_Float16)s;
          HU a, bb;
          a.h = hh;
          bb.h = (_Float16)(s - (float)hh);
          hi4[r] = a.u;
          lo4[r] = bb.u;
        }
      }
      if (WRITE_PK) {
        size_t base =
            (((size_t)b * 121 + p) * 134 + d16 * 16 + n + 3) * 16 + q * 4;
        *(u16x4*)&pout_hi[base] = hi4;
        *(u16x4*)&pout_lo[base] = lo4;
        u16x4 z = {0, 0, 0, 0};
        if (d16 == 0 && n < 3) {
          size_t hb = (((size_t)b * 121 + p) * 134 + n) * 16 + q * 4;
          *(u16x4*)&pout_hi[hb] = z;
          *(u16x4*)&pout_lo[hb] = z;
        }
        if (d16 == 7 && n >= 13) {
          size_t hb = (((size_t)b * 121 + p) * 134 + n + 118) * 16 + q * 4;
          *(u16x4*)&pout_hi[hb] = z;
          *(u16x4*)&pout_lo[hb] = z;
        }
      }
      // cpr partial: reduce over the 16 d's (n-lanes) of this block
#pragma unroll
      for (int r = 0; r < 4; ++r) {
        float v = fr[r];
        v += __shfl_xor(v, 1, 64);
        v += __shfl_xor(v, 2, 64);
        v += __shfl_xor(v, 4, 64);
        v += __shfl_xor(v, 8, 64);
        if (n == 0)
          atomicAdd(&f_out[((size_t)b * 16 + q * 4 + r) * 121 + p], v);
      }
    }
  }
}

// ---------------- both 16->16 2D convs (3x3 pad1 + relu), fused ------------
// input f3 is a raw atomic-accumulated sum -> apply relu on load.
__global__ __launch_bounds__(128) void conv2d2_kernel(
    const float* __restrict__ fin, const float* __restrict__ wgt,
    const float* __restrict__ bias, float* __restrict__ f4,
    float* __restrict__ f5) {
  const int b = blockIdx.x, t = threadIdx.x;
  __shared__ float buf0[16 * 121];
  __shared__ float buf1[16 * 121];
  const float* fb = fin + (size_t)b * 16 * 121;
  for (int idx = t; idx < 16 * 121; idx += 128)
    buf0[idx] = fmaxf(fb[idx], 0.f);
  __syncthreads();
  for (int layer = 0; layer < 2; ++layer) {
    const float* src = layer ? buf1 : buf0;
    float* dst = layer ? nullptr : buf1;
    const float* wl = wgt + layer * 2304;
    const float* bl = bias + layer * 16;
    float* go = (layer ? f5 : f4) + (size_t)b * 16 * 121;
    if (t < 121) {
      int h = t / 11, w = t - h * 11;
      float acc[16];
#pragma unroll
      for (int o = 0; o < 16; ++o) acc[o] = bl[o];
      for (int ic = 0; ic < 16; ++ic) {
#pragma unroll
        for (int u = 0; u < 3; ++u) {
          int hh = h + u - 1;
#pragma unroll
          for (int v = 0; v < 3; ++v) {
            int ww = w + v - 1;
            float val = (hh >= 0 && hh < 11 && ww >= 0 && ww < 11)
                            ? src[ic * 121 + hh * 11 + ww]
                            : 0.f;
            const float* wp = wl + ic * 9 + u * 3 + v;
#pragma unroll
            for (int o = 0; o < 16; ++o)
              acc[o] = fmaf(val, wp[o * 144], acc[o]);
          }
        }
      }
#pragma unroll
      for (int o = 0; o < 16; ++o) {
        float r = fmaxf(acc[o], 0.f);
        go[o * 121 + t] = r;
        if (dst) dst[o * 121 + t] = r;
      }
    }
    __syncthreads();
  }
}

// ---------------- sp path: seg conv -> top5 -> patch convs -> side ---------
// f_all slices may be raw sums (i=1,2) -> relu on load (identity for others).
__global__ __launch_bounds__(128) void sp_prep_kernel(
    const float* __restrict__ f_all, const float* __restrict__ x_t,
    const float* __restrict__ seg_w, const float* __restrict__ seg_b,
    const float* __restrict__ sp_wa, const float* __restrict__ sp_ba,
    const float* __restrict__ sp_wb, const float* __restrict__ sp_bb,
    const float* __restrict__ sp_sw, const float* __restrict__ sp_sb,
    float* __restrict__ sp_sd) {
  const int b = blockIdx.x, i = blockIdx.y;
  const int t = threadIdx.x;
  __shared__ float fl[16 * 121];
  __shared__ float act[121];
  __shared__ float diffs[121];
  __shared__ int sel[5];
  __shared__ float s7[7], xc7[7];
  __shared__ float P[2][7][7];
  __shared__ float y1[16][9];
  __shared__ float y2[16];

  const float* fb = f_all + ((size_t)i * 64 + b) * 16 * 121;
  for (int idx = t; idx < 16 * 121; idx += 128)
    fl[idx] = fmaxf(fb[idx], 0.f);
  __syncthreads();

  if (t < 121) {
    int h = t / 11, w = t - h * 11;
    float a = seg_b[i];
    const float* sw = seg_w + i * 144;
#pragma unroll
    for (int u = 0; u < 3; ++u) {
      int hh = h + u - 1;
#pragma unroll
      for (int v = 0; v < 3; ++v) {
        int ww = w + v - 1;
        if (hh >= 0 && hh < 11 && ww >= 0 && ww < 11) {
          int pp = hh * 11 + ww;
          for (int ic = 0; ic < 16; ++ic)
            a = fmaf(fl[ic * 121 + pp], sw[ic * 9 + u * 3 + v], a);
        }
      }
    }
    act[t] = a;
  }
  __syncthreads();
  if (t < 121) diffs[t] = fabsf(act[t] - act[60]);
  __syncthreads();

  for (int k = 0; k < 5; ++k) {
    if (t < 64) {
      float d0 = diffs[t];
      int i0 = t;
      float d1 = (t + 64 < 121) ? diffs[t + 64] : 3.0e38f;
      if (d1 < d0) { d0 = d1; i0 = t + 64; }
#pragma unroll
      for (int off = 32; off; off >>= 1) {
        float od = __shfl_down(d0, off, 64);
        int oi = __shfl_down(i0, off, 64);
        if (od < d0 || (od == d0 && oi < i0)) { d0 = od; i0 = oi; }
      }
      if (t == 0) {
        sel[k] = i0;
        diffs[i0] = 3.0e38f;
      }
    }
    __syncthreads();
  }

  if (t < 7) {
    const float* xb = x_t + (size_t)b * 121 * 128;
    float s = 0.f;
    for (int k = 0; k < 5; ++k) s += xb[(size_t)sel[k] * 128 + 61 + t];
    s7[t] = s;
    xc7[t] = xb[60 * 128 + 61 + t];
  }
  __syncthreads();
  if (t < 49) {
    int r = t / 7, c = t - r * 7;
    float d0 = s7[c];
    if (fabsf(d0) < 0.01f) d0 = 0.01f;
    float d1 = xc7[c];
    if (fabsf(d1) < 0.01f) d1 = 0.01f;
    P[0][r][c] = s7[r] / d0;
    P[1][r][c] = xc7[r] / d1;
  }
  __syncthreads();
  for (int item = t; item < 144; item += 128) {
    int ch = item / 9, pos = item - ch * 9;
    int a0 = pos / 3, b0 = pos - a0 * 3;
    float a = sp_ba[i * 16 + ch];
    const float* wa = sp_wa + ((size_t)(i * 16 + ch) * 2) * 9;
#pragma unroll
    for (int icc = 0; icc < 2; ++icc)
#pragma unroll
      for (int u = 0; u < 3; ++u)
#pragma unroll
        for (int v = 0; v < 3; ++v)
          a = fmaf(P[icc][2 * a0 + u][2 * b0 + v], wa[icc * 9 + u * 3 + v], a);
    y1[ch][pos] = fmaxf(a, 0.f);
  }
  __syncthreads();
  if (t < 16) {
    float a = sp_bb[i * 16 + t];
    const float* wb = sp_wb + (size_t)(i * 16 + t) * 16 * 9;
    for (int ch = 0; ch < 16; ++ch)
#pragma unroll
      for (int pos = 0; pos < 9; ++pos)
        a = fmaf(y1[ch][pos], wb[ch * 9 + pos], a);
    y2[t] = fmaxf(a, 0.f);
  }
  __syncthreads();
  if (t < 16) {
    float a = sp_sb[i * 16 + t];
    const float* swp = sp_sw + (size_t)(i * 16 + t) * 16;
    for (int ch = 0; ch < 16; ++ch) a = fmaf(y2[ch], swp[ch], a);
    sp_sd[((size_t)i * 64 + b) * 16 + t] = a;
  }
}

// ---------------- final fuse (relu on center reads — exact for all feats) --
__global__ __launch_bounds__(256) void fuse_kernel(
    const float* __restrict__ f_all, const float* __restrict__ sp_sd,
    const float* __restrict__ so_w, const float* __restrict__ so_b,
    const float* __restrict__ fp, float* __restrict__ out) {
  int g = blockIdx.x * 256 + threadIdx.x;
  if (g >= 1024) return;
  int b = g >> 4, o = g & 15;
  float tot = 0.f;
  for (int i = 0; i < 5; ++i) {
    float s = so_b[i * 16 + o];
    for (int c = 0; c < 16; ++c)
      s += fmaxf(f_all[(((size_t)i * 64 + b) * 16 + c) * 121 + 60], 0.f) *
           so_w[(i * 16 + o) * 16 + c];
    tot += fp[i] * s;
    tot += fp[5 + i] * sp_sd[((size_t)i * 64 + b) * 16 + o];
  }
  out[g] = tot;
}

extern "C" void kernel_launch(void* const* d_in, const int* in_sizes, int n_in,
                              void* d_out, int out_size, void* d_ws,
                              size_t ws_size, hipStream_t stream) {
  const float* x = (const float*)d_in[0];
  const float* w3d1 = (const float*)d_in[1];
  const float* b3d1 = (const float*)d_in[2];
  const float* w3d23 = (const float*)d_in[3];
  const float* b3d23 = (const float*)d_in[4];
  const float* cpr_w = (const float*)d_in[5];
  const float* w2d45 = (const float*)d_in[6];
  const float* b2d45 = (const float*)d_in[7];
  const float* seg_w = (const float*)d_in[8];
  const float* seg_b = (const float*)d_in[9];
  const float* so_w = (const float*)d_in[10];
  const float* so_b = (const float*)d_in[11];
  const float* sp_wa = (const float*)d_in[12];
  const float* sp_ba = (const float*)d_in[13];
  const float* sp_wb = (const float*)d_in[14];
  const float* sp_bb = (const float*)d_in[15];
  const float* sp_sw = (const float*)d_in[16];
  const float* sp_sb = (const float*)d_in[17];
  const float* fpar = (const float*)d_in[18];

  float* ws = (float*)d_ws;
  float* x_t = ws;                       // 991232 f
  float* a_sm = x_t + 991232;            // 6144 f
  float* f_all = a_sm + 6144;            // 619520 f
  float* sp_sd = f_all + 619520;         // 5120 f
  float* wrep1 = sp_sd + 5120;           // 1024 f
  unsigned short* pk1h = (unsigned short*)(wrep1 + 1024);
  unsigned short* pk1l = pk1h + PKE;
  unsigned short* pk2h = pk1l + PKE;
  unsigned short* pk2l = pk2h + PKE;
  unsigned short* arep = pk2l + PKE;     // 65536 u16

  transpose_kernel<<<64, 256, 0, stream>>>(x, x_t);
  softmax_kernel<<<48, 128, 0, stream>>>(cpr_w, a_sm);
  repack1_kernel<<<4, 256, 0, stream>>>(w3d1, wrep1);
  arep_kernel<<<256, 256, 0, stream>>>(w3d23, arep);
  zerof_kernel<<<968, 256, 0, stream>>>(f_all + F_SLICE);

  conv1_kernel<<<dim3(33, 64), 256, 0, stream>>>(x_t, wrep1, b3d1, a_sm, pk1h,
                                                 pk1l, f_all);
  conv_mfma_kernel<true><<<dim3(6, 8, 64), 512, 0, stream>>>(
      pk1h, pk1l, arep, b3d23, a_sm + 2048, pk2h, pk2l, f_all + F_SLICE);
  conv_mfma_kernel<false><<<dim3(6, 8, 64), 512, 0, stream>>>(
      pk2h, pk2l, arep + 32768, b3d23 + 16, a_sm + 4096, nullptr, nullptr,
      f_all + 2 * F_SLICE);

  conv2d2_kernel<<<64, 128, 0, stream>>>(f_all + 2 * F_SLICE, w2d45, b2d45,
                                         f_all + 3 * F_SLICE,
                                         f_all + 4 * F_SLICE);

  sp_prep_kernel<<<dim3(64, 5), 128, 0, stream>>>(
      f_all, x_t, seg_w, seg_b, sp_wa, sp_ba, sp_wb, sp_bb, sp_sw, sp_sb,
      sp_sd);
  fuse_kernel<<<4, 256, 0, stream>>>(f_all, sp_sd, so_w, so_b, fpar,
                                     (float*)d_out);
}

// Round 8
// 495.246 us; speedup vs baseline: 2.8025x; 1.0225x over previous
//
#include <hip/hip_runtime.h>
#include <hip/hip_bf16.h>

// ---------------------------------------------------------------------------
// Segment_3DCenter round 8: conv2/conv3 MFMA f16 hi/lo split, flattened grid
// (round 7) + kw/tt sliding-window B-frag reuse. K repacked as 36 chunks =
// (kh 3) x (kd-pair 4, kd=7 zero-padded) x (kw 3); the B-fragment address is
// then kw-independent, so per (kh,kdp) group a wave loads 5 column-frags
// (hi+lo = 10 ds_read_b128) and reuses them across 9 MFMA triples
// (192 -> 120 LDS reads per pass; MFMAs 288 -> 324).
// pk stored as separate hi/lo u16 planes: pk[b][p][rawd 134][ic 16] (x256).
// cpr partials via atomicAdd into zeroed f_all; consumers relu on load.
// ---------------------------------------------------------------------------

#define F_SLICE (64 * 16 * 121)          // 123904
#define PKE (64 * 121 * 134 * 16)        // u16 elements per pk plane
#define LHALF 18304                      // LDS halves per part (52*352)
#define AREP_CV 36864                    // u16 per conv in arep (36*2*64*8)

typedef _Float16 half8 __attribute__((ext_vector_type(8)));
typedef float float4v __attribute__((ext_vector_type(4)));
typedef unsigned short u16x8 __attribute__((ext_vector_type(8)));
typedef unsigned short u16x4 __attribute__((ext_vector_type(4)));

union HU { _Float16 h; unsigned short u; };

// ---------------- transpose x: [b][c][p] -> [b][p][c], LDS-tiled -----------
__global__ __launch_bounds__(256) void transpose_kernel(
    const float* __restrict__ x, float* __restrict__ x_t) {
  __shared__ float tile[128][123];
  int b = blockIdx.x, t = threadIdx.x;
  const float* xb = x + (size_t)b * 128 * 121;
  for (int idx = t; idx < 128 * 121; idx += 256) {
    int c = idx / 121, p = idx - c * 121;
    tile[c][p] = xb[idx];
  }
  __syncthreads();
  float* ob = x_t + (size_t)b * 121 * 128;
  for (int idx = t; idx < 121 * 128; idx += 256) {
    int p = idx >> 7, c = idx & 127;
    ob[idx] = tile[c][p];
  }
}

// ---------------- softmax over last dim of cpr_w (48 rows x 128) -----------
__global__ __launch_bounds__(128) void softmax_kernel(
    const float* __restrict__ w, float* __restrict__ a) {
  int row = blockIdx.x, t = threadIdx.x;
  __shared__ float red[128];
  float v = w[row * 128 + t];
  red[t] = v;
  __syncthreads();
  for (int s = 64; s; s >>= 1) {
    if (t < s) red[t] = fmaxf(red[t], red[t + s]);
    __syncthreads();
  }
  float m = red[0];
  __syncthreads();
  float e = expf(v - m);
  red[t] = e;
  __syncthreads();
  for (int s = 64; s; s >>= 1) {
    if (t < s) red[t] += red[t + s];
    __syncthreads();
  }
  a[row * 128 + t] = e / red[0];
}

// ---------------- zero f_all slices 1,2 (atomic accumulation targets) ------
__global__ __launch_bounds__(256) void zerof_kernel(float* __restrict__ p) {
  int i = blockIdx.x * 256 + threadIdx.x;
  if (i < 2 * F_SLICE) p[i] = 0.f;
}

// ---------------- repack conv1 weights (fp32 path) -------------------------
__global__ __launch_bounds__(256) void repack1_kernel(
    const float* __restrict__ w3d1, float* __restrict__ wrep1) {
  int r = blockIdx.x * 256 + threadIdx.x;
  if (r < 1008) {
    int j = r;
    int kw = j % 3; j /= 3;
    int o = j % 8; j /= 8;
    int kh = j % 3; j /= 3;
    int kd = j % 7; j /= 7;
    int gg = j;
    wrep1[r] = w3d1[(gg * 8 + o) * 63 + kd * 9 + kh * 3 + kw];
  }
}

// ---------------- repack conv2/3 weights into MFMA A-frag layout -----------
// arep[cv 2][chunk 36][part 2][lane 64][j 8] f16, scaled x256.
// chunk = (kh*4 + kdp)*3 + kw; k 0..15 -> kd=2kdp, k 16..31 -> kd=2kdp+1
// (kd=7 zero). lane: m=oc=lane&15, q=lane>>4; kd-half = q>>1, ic-half = q&1.
__global__ __launch_bounds__(256) void arep_kernel(
    const float* __restrict__ w3d23, unsigned short* __restrict__ arep) {
  int idx = blockIdx.x * 256 + threadIdx.x;  // 0..73727
  if (idx >= 2 * AREP_CV) return;
  int j = idx & 7;
  int lane = (idx >> 3) & 63;
  int part = (idx >> 9) & 1;
  int rem = idx >> 10;  // 0..71
  int chunk = rem % 36;
  int cv = rem / 36;
  int kw = chunk % 3;
  int grp = chunk / 3;
  int kdp = grp & 3;
  int kh = grp >> 2;
  int m = lane & 15, q = lane >> 4;
  int kd = 2 * kdp + (q >> 1);
  int ic = (q & 1) * 8 + j;
  float w = 0.f;
  if (kd < 7)
    w = w3d23[((cv * 16 + m) * 16 + ic) * 63 + kd * 9 + kh * 3 + kw] * 256.f;
  _Float16 hi = (_Float16)w;
  HU out;
  out.h = (part == 0) ? hi : (_Float16)(w - (float)hi);
  arep[idx] = out.u;
}

// ---------------- conv1 (ic=1) fp32: x_t -> pk1 planes (+fused cpr f1) -----
__global__ __launch_bounds__(256, 4) void conv1_kernel(
    const float* __restrict__ in, const float* __restrict__ wrep,
    const float* __restrict__ bias, const float* __restrict__ al,
    unsigned short* __restrict__ pk_hi, unsigned short* __restrict__ pk_lo,
    float* __restrict__ f_out) {
  __shared__ float in_lds[18][134];
  __shared__ float red[2][16][4];
  const int t = threadIdx.x;
  const int bx = blockIdx.x;
  const int b = blockIdx.y;
  const int h = bx / 3;
  const int w0 = (bx % 3) * 4;
  const int lane = t & 63;
  const int wv = t >> 6;
  const int dh = wv & 1;
  const int dd = lane + (dh << 6);
  const int g = __builtin_amdgcn_readfirstlane(wv >> 1);
  const int oc_base = g << 3;

  float acc[8][4];
#pragma unroll
  for (int o = 0; o < 8; ++o)
#pragma unroll
    for (int c = 0; c < 4; ++c) acc[o][c] = 0.f;

  const int ds = t & 127;
  const int half = t >> 7;

  for (int r = half; r < 18; r += 2) {
    int hr = r / 6;
    int wc = r - hr * 6;
    int hh = h - 1 + hr;
    int ww = w0 - 1 + wc;
    bool ok = (hh >= 0) & (hh < 11) & (ww >= 0) & (ww < 11);
    const float* src = in + (((size_t)b) * 121 + hh * 11 + ww) * 128;
    float v = 0.f;
    if (ok && ds >= 3) v = src[ds - 3];
    in_lds[r][ds] = v;
    if (ds < 6) {
      float v2 = 0.f;
      if (ok && ds < 3) v2 = src[125 + ds];
      in_lds[r][128 + ds] = v2;
    }
  }
  __syncthreads();
  const float* wbase = wrep + g * 504;
#pragma unroll
  for (int kd = 0; kd < 7; ++kd) {
#pragma unroll
    for (int kh = 0; kh < 3; ++kh) {
      float ws[24];
      const float* wp = wbase + kd * 72 + kh * 24;
#pragma unroll
      for (int j = 0; j < 24; ++j) ws[j] = wp[j];
      float v[6];
#pragma unroll
      for (int qq = 0; qq < 6; ++qq) v[qq] = in_lds[kh * 6 + qq][dd + kd];
#pragma unroll
      for (int o = 0; o < 8; ++o)
#pragma unroll
        for (int kw = 0; kw < 3; ++kw) {
          float wv_ = ws[o * 3 + kw];
#pragma unroll
          for (int c = 0; c < 4; ++c)
            acc[o][c] = fmaf(wv_, v[kw + c], acc[o][c]);
        }
    }
  }

  const int p0 = h * 11 + w0;
#pragma unroll
  for (int o = 0; o < 8; ++o) {
    float bv = bias[oc_base + o];
#pragma unroll
    for (int c = 0; c < 4; ++c) acc[o][c] = fmaxf(acc[o][c] + bv, 0.f);
  }
#pragma unroll
  for (int c = 0; c < 4; ++c) {
    if (w0 + c < 11) {
      u16x8 hi8, lo8;
#pragma unroll
      for (int o = 0; o < 8; ++o) {
        float s = acc[o][c] * 256.f;
        _Float16 hh = (_Float16)s;
        HU a, bb;
        a.h = hh;
        bb.h = (_Float16)(s - (float)hh);
        hi8[o] = a.u;
        lo8[o] = bb.u;
      }
      size_t base = (((size_t)b * 121 + p0 + c) * 134 + dd + 3) * 16 + oc_base;
      *(u16x8*)&pk_hi[base] = hi8;
      *(u16x8*)&pk_lo[base] = lo8;
    }
  }
  if (dd < 3) {
    u16x8 z = {0, 0, 0, 0, 0, 0, 0, 0};
#pragma unroll
    for (int c = 0; c < 4; ++c) {
      if (w0 + c < 11) {
        size_t b0 = (((size_t)b * 121 + p0 + c) * 134 + dd) * 16 + oc_base;
        size_t b1 =
            (((size_t)b * 121 + p0 + c) * 134 + 131 + dd) * 16 + oc_base;
        *(u16x8*)&pk_hi[b0] = z;
        *(u16x8*)&pk_lo[b0] = z;
        *(u16x8*)&pk_hi[b1] = z;
        *(u16x8*)&pk_lo[b1] = z;
      }
    }
  }
  float alv[8];
#pragma unroll
  for (int o = 0; o < 8; ++o) alv[o] = al[(oc_base + o) * 128 + dd];
#pragma unroll
  for (int o = 0; o < 8; ++o) {
#pragma unroll
    for (int c = 0; c < 4; ++c) {
      float pv = acc[o][c] * alv[o];
#pragma unroll
      for (int off = 32; off; off >>= 1) pv += __shfl_down(pv, off, 64);
      if (lane == 0) red[dh][oc_base + o][c] = pv;
    }
  }
  __syncthreads();
  if (t < 64) {
    int oc = t >> 2, c = t & 3;
    if (w0 + c < 11)
      f_out[((size_t)b * 16 + oc) * 121 + p0 + c] =
          fmaxf(red[0][oc][c] + red[1][oc][c], 0.f);
  }
}

// ---------------- conv2/conv3: MFMA f16x2-split, window-reuse K-loop -------
// Block = (bx h-pair, d16, b), 512 thr = 8 waves: hs = wave>>2, wg = wave&3.
// LDS: two part planes of 18304 halves; unit u (0..4575) at bytes u*16:
// u = part*2288 + (panel*2+icq)*22 + dloc, panel = rr*13+cc (4 rows x 13 w).
template <bool WRITE_PK>
__global__ __launch_bounds__(512, 2) void conv_mfma_kernel(
    const unsigned short* __restrict__ pin_hi,
    const unsigned short* __restrict__ pin_lo,
    const unsigned short* __restrict__ arep, const float* __restrict__ bias,
    const float* __restrict__ al, unsigned short* __restrict__ pout_hi,
    unsigned short* __restrict__ pout_lo, float* __restrict__ f_out) {
  __shared__ _Float16 lds[2 * LHALF];
  const int t = threadIdx.x;
  const int bx = blockIdx.x, d16 = blockIdx.y, b = blockIdx.z;
  const int lane = t & 63, wave = t >> 6;
  const int n = lane & 15, q = lane >> 4;
  const int hs = wave >> 2, wg = wave & 3;
  const int h = 2 * bx + hs;  // 0..11 (11 = dummy)

  // ---- staging: 4576 16-B units, pure copy (planes pre-split hi/lo) ----
#pragma unroll
  for (int i = 0; i < 9; ++i) {
    int u = t + i * 512;
    if (u < 4576) {
      int part = (u >= 2288) ? 1 : 0;
      int qq = u - part * 2288;
      int pc = qq / 22;
      int dloc = qq - pc * 22;
      int panel = pc >> 1, icq = pc & 1;
      int rr = panel / 13, cc = panel - rr * 13;
      int hh = 2 * bx + rr - 1, ww = cc - 1;
      bool ok = (hh >= 0) & (hh < 11) & (ww >= 0) & (ww < 11);
      u16x8 v = {0, 0, 0, 0, 0, 0, 0, 0};
      if (ok) {
        const unsigned short* src = part ? pin_lo : pin_hi;
        v = *(const u16x8*)&src[(((size_t)b * 121 + hh * 11 + ww) * 134 +
                                d16 * 16 + dloc) *
                                   16 +
                               icq * 8];
      }
      *(u16x8*)&lds[(size_t)u * 8] = v;
    }
  }
  float bias_r[4], alr[4];
#pragma unroll
  for (int r = 0; r < 4; ++r) {
    bias_r[r] = bias[q * 4 + r];
    alr[r] = al[(q * 4 + r) * 128 + d16 * 16 + n];
  }
  __syncthreads();

  // ---- compute: window-reuse over (kh, kd-pair) groups ----
  const int wl0 = wg * 3;
  int cb[5], cbk[5];
  const int base_qn = (q & 1) * 176 + n * 8 + hs * 4576;
  const int kdh = (lane & 32) ? 8 : 0;
#pragma unroll
  for (int j = 0; j < 5; ++j) {
    int colj = wl0 + j;
    if (colj > 12) colj = 12;  // dummy-only column, result discarded
    cb[j] = base_qn + colj * 352;
    cbk[j] = cb[j] + kdh;
  }

  float4v acc[3];
#pragma unroll
  for (int tt = 0; tt < 3; ++tt) acc[tt] = (float4v){0.f, 0.f, 0.f, 0.f};

#pragma unroll
  for (int kh = 0; kh < 3; ++kh) {
#pragma unroll
    for (int kdp = 0; kdp < 4; ++kdp) {
      half8 whi[5], wlo[5];
#pragma unroll
      for (int j = 0; j < 5; ++j) {
        // kdp==3 pairs kd6 with zero kd7: both halves read kd6 (A half = 0)
        int a = ((kdp < 3) ? cbk[j] : cb[j]) + kh * 4576 + kdp * 16;
        whi[j] = *(const half8*)&lds[a];
        wlo[j] = *(const half8*)&lds[a + LHALF];
      }
#pragma unroll
      for (int kw = 0; kw < 3; ++kw) {
        const int c2 = (kh * 4 + kdp) * 3 + kw;
        half8 ahi = *(const half8*)&arep[((c2 * 2 + 0) * 64 + lane) * 8];
        half8 alo = *(const half8*)&arep[((c2 * 2 + 1) * 64 + lane) * 8];
#pragma unroll
        for (int tt = 0; tt < 3; ++tt) {
          const int jj = tt + kw;
          acc[tt] = __builtin_amdgcn_mfma_f32_16x16x32_f16(ahi, whi[jj],
                                                           acc[tt], 0, 0, 0);
          acc[tt] = __builtin_amdgcn_mfma_f32_16x16x32_f16(ahi, wlo[jj],
                                                           acc[tt], 0, 0, 0);
          acc[tt] = __builtin_amdgcn_mfma_f32_16x16x32_f16(alo, whi[jj],
                                                           acc[tt], 0, 0, 0);
        }
      }
    }
  }

  // ---- epilogue ----
#pragma unroll
  for (int tt = 0; tt < 3; ++tt) {
    const int wl = wg * 3 + tt;
    if (h < 11 && wl < 11) {
      const int p = h * 11 + wl;
      float fr[4];
      u16x4 hi4, lo4;
#pragma unroll
      for (int r = 0; r < 4; ++r) {
        float sv = fmaxf(acc[tt][r] * (1.f / 65536.f) + bias_r[r], 0.f);
        fr[r] = sv * alr[r];
        if (WRITE_PK) {
          float s = sv * 256.f;
          _Float16 hh = (_Float16)s;
          HU a, bb;
          a.h = hh;
          bb.h = (_Float16)(s - (float)hh);
          hi4[r] = a.u;
          lo4[r] = bb.u;
        }
      }
      if (WRITE_PK) {
        size_t base =
            (((size_t)b * 121 + p) * 134 + d16 * 16 + n + 3) * 16 + q * 4;
        *(u16x4*)&pout_hi[base] = hi4;
        *(u16x4*)&pout_lo[base] = lo4;
        u16x4 z = {0, 0, 0, 0};
        if (d16 == 0 && n < 3) {
          size_t hb = (((size_t)b * 121 + p) * 134 + n) * 16 + q * 4;
          *(u16x4*)&pout_hi[hb] = z;
          *(u16x4*)&pout_lo[hb] = z;
        }
        if (d16 == 7 && n >= 13) {
          size_t hb = (((size_t)b * 121 + p) * 134 + n + 118) * 16 + q * 4;
          *(u16x4*)&pout_hi[hb] = z;
          *(u16x4*)&pout_lo[hb] = z;
        }
      }
      // cpr partial: reduce over the 16 d's (n-lanes) of this block
#pragma unroll
      for (int r = 0; r < 4; ++r) {
        float v = fr[r];
        v += __shfl_xor(v, 1, 64);
        v += __shfl_xor(v, 2, 64);
        v += __shfl_xor(v, 4, 64);
        v += __shfl_xor(v, 8, 64);
        if (n == 0)
          atomicAdd(&f_out[((size_t)b * 16 + q * 4 + r) * 121 + p], v);
      }
    }
  }
}

// ---------------- both 16->16 2D convs (3x3 pad1 + relu), fused ------------
// input f3 is a raw atomic-accumulated sum -> apply relu on load.
__global__ __launch_bounds__(128) void conv2d2_kernel(
    const float* __restrict__ fin, const float* __restrict__ wgt,
    const float* __restrict__ bias, float* __restrict__ f4,
    float* __restrict__ f5) {
  const int b = blockIdx.x, t = threadIdx.x;
  __shared__ float buf0[16 * 121];
  __shared__ float buf1[16 * 121];
  const float* fb = fin + (size_t)b * 16 * 121;
  for (int idx = t; idx < 16 * 121; idx += 128)
    buf0[idx] = fmaxf(fb[idx], 0.f);
  __syncthreads();
  for (int layer = 0; layer < 2; ++layer) {
    const float* src = layer ? buf1 : buf0;
    float* dst = layer ? nullptr : buf1;
    const float* wl = wgt + layer * 2304;
    const float* bl = bias + layer * 16;
    float* go = (layer ? f5 : f4) + (size_t)b * 16 * 121;
    if (t < 121) {
      int h = t / 11, w = t - h * 11;
      float acc[16];
#pragma unroll
      for (int o = 0; o < 16; ++o) acc[o] = bl[o];
      for (int ic = 0; ic < 16; ++ic) {
#pragma unroll
        for (int u = 0; u < 3; ++u) {
          int hh = h + u - 1;
#pragma unroll
          for (int v = 0; v < 3; ++v) {
            int ww = w + v - 1;
            float val = (hh >= 0 && hh < 11 && ww >= 0 && ww < 11)
                            ? src[ic * 121 + hh * 11 + ww]
                            : 0.f;
            const float* wp = wl + ic * 9 + u * 3 + v;
#pragma unroll
            for (int o = 0; o < 16; ++o)
              acc[o] = fmaf(val, wp[o * 144], acc[o]);
          }
        }
      }
#pragma unroll
      for (int o = 0; o < 16; ++o) {
        float r = fmaxf(acc[o], 0.f);
        go[o * 121 + t] = r;
        if (dst) dst[o * 121 + t] = r;
      }
    }
    __syncthreads();
  }
}

// ---------------- sp path: seg conv -> top5 -> patch convs -> side ---------
// f_all slices may be raw sums (i=1,2) -> relu on load (identity for others).
__global__ __launch_bounds__(128) void sp_prep_kernel(
    const float* __restrict__ f_all, const float* __restrict__ x_t,
    const float* __restrict__ seg_w, const float* __restrict__ seg_b,
    const float* __restrict__ sp_wa, const float* __restrict__ sp_ba,
    const float* __restrict__ sp_wb, const float* __restrict__ sp_bb,
    const float* __restrict__ sp_sw, const float* __restrict__ sp_sb,
    float* __restrict__ sp_sd) {
  const int b = blockIdx.x, i = blockIdx.y;
  const int t = threadIdx.x;
  __shared__ float fl[16 * 121];
  __shared__ float act[121];
  __shared__ float diffs[121];
  __shared__ int sel[5];
  __shared__ float s7[7], xc7[7];
  __shared__ float P[2][7][7];
  __shared__ float y1[16][9];
  __shared__ float y2[16];

  const float* fb = f_all + ((size_t)i * 64 + b) * 16 * 121;
  for (int idx = t; idx < 16 * 121; idx += 128)
    fl[idx] = fmaxf(fb[idx], 0.f);
  __syncthreads();

  if (t < 121) {
    int h = t / 11, w = t - h * 11;
    float a = seg_b[i];
    const float* sw = seg_w + i * 144;
#pragma unroll
    for (int u = 0; u < 3; ++u) {
      int hh = h + u - 1;
#pragma unroll
      for (int v = 0; v < 3; ++v) {
        int ww = w + v - 1;
        if (hh >= 0 && hh < 11 && ww >= 0 && ww < 11) {
          int pp = hh * 11 + ww;
          for (int ic = 0; ic < 16; ++ic)
            a = fmaf(fl[ic * 121 + pp], sw[ic * 9 + u * 3 + v], a);
        }
      }
    }
    act[t] = a;
  }
  __syncthreads();
  if (t < 121) diffs[t] = fabsf(act[t] - act[60]);
  __syncthreads();

  for (int k = 0; k < 5; ++k) {
    if (t < 64) {
      float d0 = diffs[t];
      int i0 = t;
      float d1 = (t + 64 < 121) ? diffs[t + 64] : 3.0e38f;
      if (d1 < d0) { d0 = d1; i0 = t + 64; }
#pragma unroll
      for (int off = 32; off; off >>= 1) {
        float od = __shfl_down(d0, off, 64);
        int oi = __shfl_down(i0, off, 64);
        if (od < d0 || (od == d0 && oi < i0)) { d0 = od; i0 = oi; }
      }
      if (t == 0) {
        sel[k] = i0;
        diffs[i0] = 3.0e38f;
      }
    }
    __syncthreads();
  }

  if (t < 7) {
    const float* xb = x_t + (size_t)b * 121 * 128;
    float s = 0.f;
    for (int k = 0; k < 5; ++k) s += xb[(size_t)sel[k] * 128 + 61 + t];
    s7[t] = s;
    xc7[t] = xb[60 * 128 + 61 + t];
  }
  __syncthreads();
  if (t < 49) {
    int r = t / 7, c = t - r * 7;
    float d0 = s7[c];
    if (fabsf(d0) < 0.01f) d0 = 0.01f;
    float d1 = xc7[c];
    if (fabsf(d1) < 0.01f) d1 = 0.01f;
    P[0][r][c] = s7[r] / d0;
    P[1][r][c] = xc7[r] / d1;
  }
  __syncthreads();
  for (int item = t; item < 144; item += 128) {
    int ch = item / 9, pos = item - ch * 9;
    int a0 = pos / 3, b0 = pos - a0 * 3;
    float a = sp_ba[i * 16 + ch];
    const float* wa = sp_wa + ((size_t)(i * 16 + ch) * 2) * 9;
#pragma unroll
    for (int icc = 0; icc < 2; ++icc)
#pragma unroll
      for (int u = 0; u < 3; ++u)
#pragma unroll
        for (int v = 0; v < 3; ++v)
          a = fmaf(P[icc][2 * a0 + u][2 * b0 + v], wa[icc * 9 + u * 3 + v], a);
    y1[ch][pos] = fmaxf(a, 0.f);
  }
  __syncthreads();
  if (t < 16) {
    float a = sp_bb[i * 16 + t];
    const float* wb = sp_wb + (size_t)(i * 16 + t) * 16 * 9;
    for (int ch = 0; ch < 16; ++ch)
#pragma unroll
      for (int pos = 0; pos < 9; ++pos)
        a = fmaf(y1[ch][pos], wb[ch * 9 + pos], a);
    y2[t] = fmaxf(a, 0.f);
  }
  __syncthreads();
  if (t < 16) {
    float a = sp_sb[i * 16 + t];
    const float* swp = sp_sw + (size_t)(i * 16 + t) * 16;
    for (int ch = 0; ch < 16; ++ch) a = fmaf(y2[ch], swp[ch], a);
    sp_sd[((size_t)i * 64 + b) * 16 + t] = a;
  }
}

// ---------------- final fuse (relu on center reads — exact for all feats) --
__global__ __launch_bounds__(256) void fuse_kernel(
    const float* __restrict__ f_all, const float* __restrict__ sp_sd,
    const float* __restrict__ so_w, const float* __restrict__ so_b,
    const float* __restrict__ fp, float* __restrict__ out) {
  int g = blockIdx.x * 256 + threadIdx.x;
  if (g >= 1024) return;
  int b = g >> 4, o = g & 15;
  float tot = 0.f;
  for (int i = 0; i < 5; ++i) {
    float s = so_b[i * 16 + o];
    for (int c = 0; c < 16; ++c)
      s += fmaxf(f_all[(((size_t)i * 64 + b) * 16 + c) * 121 + 60], 0.f) *
           so_w[(i * 16 + o) * 16 + c];
    tot += fp[i] * s;
    tot += fp[5 + i] * sp_sd[((size_t)i * 64 + b) * 16 + o];
  }
  out[g] = tot;
}

extern "C" void kernel_launch(void* const* d_in, const int* in_sizes, int n_in,
                              void* d_out, int out_size, void* d_ws,
                              size_t ws_size, hipStream_t stream) {
  const float* x = (const float*)d_in[0];
  const float* w3d1 = (const float*)d_in[1];
  const float* b3d1 = (const float*)d_in[2];
  const float* w3d23 = (const float*)d_in[3];
  const float* b3d23 = (const float*)d_in[4];
  const float* cpr_w = (const float*)d_in[5];
  const float* w2d45 = (const float*)d_in[6];
  const float* b2d45 = (const float*)d_in[7];
  const float* seg_w = (const float*)d_in[8];
  const float* seg_b = (const float*)d_in[9];
  const float* so_w = (const float*)d_in[10];
  const float* so_b = (const float*)d_in[11];
  const float* sp_wa = (const float*)d_in[12];
  const float* sp_ba = (const float*)d_in[13];
  const float* sp_wb = (const float*)d_in[14];
  const float* sp_bb = (const float*)d_in[15];
  const float* sp_sw = (const float*)d_in[16];
  const float* sp_sb = (const float*)d_in[17];
  const float* fpar = (const float*)d_in[18];

  float* ws = (float*)d_ws;
  float* x_t = ws;                       // 991232 f
  float* a_sm = x_t + 991232;            // 6144 f
  float* f_all = a_sm + 6144;            // 619520 f
  float* sp_sd = f_all + 619520;         // 5120 f
  float* wrep1 = sp_sd + 5120;           // 1024 f
  unsigned short* pk1h = (unsigned short*)(wrep1 + 1024);
  unsigned short* pk1l = pk1h + PKE;
  unsigned short* pk2h = pk1l + PKE;
  unsigned short* pk2l = pk2h + PKE;
  unsigned short* arep = pk2l + PKE;     // 2*AREP_CV u16

  transpose_kernel<<<64, 256, 0, stream>>>(x, x_t);
  softmax_kernel<<<48, 128, 0, stream>>>(cpr_w, a_sm);
  repack1_kernel<<<4, 256, 0, stream>>>(w3d1, wrep1);
  arep_kernel<<<288, 256, 0, stream>>>(w3d23, arep);
  zerof_kernel<<<968, 256, 0, stream>>>(f_all + F_SLICE);

  conv1_kernel<<<dim3(33, 64), 256, 0, stream>>>(x_t, wrep1, b3d1, a_sm, pk1h,
                                                 pk1l, f_all);
  conv_mfma_kernel<true><<<dim3(6, 8, 64), 512, 0, stream>>>(
      pk1h, pk1l, arep, b3d23, a_sm + 2048, pk2h, pk2l, f_all + F_SLICE);
  conv_mfma_kernel<false><<<dim3(6, 8, 64), 512, 0, stream>>>(
      pk2h, pk2l, arep + AREP_CV, b3d23 + 16, a_sm + 4096, nullptr, nullptr,
      f_all + 2 * F_SLICE);

  conv2d2_kernel<<<64, 128, 0, stream>>>(f_all + 2 * F_SLICE, w2d45, b2d45,
                                         f_all + 3 * F_SLICE,
                                         f_all + 4 * F_SLICE);

  sp_prep_kernel<<<dim3(64, 5), 128, 0, stream>>>(
      f_all, x_t, seg_w, seg_b, sp_wa, sp_ba, sp_wb, sp_bb, sp_sw, sp_sb,
      sp_sd);
  fuse_kernel<<<4, 256, 0, stream>>>(f_all, sp_sd, so_w, so_b, fpar,
                                     (float*)d_out);
}

// Round 9
// 485.239 us; speedup vs baseline: 2.8603x; 1.0206x over previous
//
#include <hip/hip_runtime.h>
#include <hip/hip_bf16.h>

// ---------------------------------------------------------------------------
// Segment_3DCenter round 9: round-8 structure +
//  (1) conv_mfma staging via __builtin_amdgcn_global_load_lds (width 16):
//      LDS layout is affine (unit u at byte u*16, u = t + i*512), so the
//      wave-uniform-base + lane*16 DMA constraint holds exactly. Halo lanes
//      pre-zero their slot. Removes 73 KB/block of ds_write from the LDS pipe
//      (which is ~45% busy with B-frag reads) and the VGPR round-trip.
//  (2) conv2d2 weights repacked [layer][ic][uv][oc16] -> batched s_loads
//      (was 16 scattered s_loads per tap, lgkm-serialized).
//  (3) sp_prep seg-conv loop reorder -> 9-consecutive weight loads.
//  (4) zerof folded into conv1 (one fewer launch).
// ---------------------------------------------------------------------------

#define F_SLICE (64 * 16 * 121)          // 123904
#define PKE (64 * 121 * 134 * 16)        // u16 elements per pk plane
#define LHALF 18304                      // LDS halves per part (52*352)
#define AREP_CV 36864                    // u16 per conv in arep (36*2*64*8)

typedef _Float16 half8 __attribute__((ext_vector_type(8)));
typedef float float4v __attribute__((ext_vector_type(4)));
typedef unsigned short u16x8 __attribute__((ext_vector_type(8)));
typedef unsigned short u16x4 __attribute__((ext_vector_type(4)));

typedef __attribute__((address_space(1))) unsigned int gu32;
typedef __attribute__((address_space(3))) unsigned int lu32;

union HU { _Float16 h; unsigned short u; };

// ---------------- transpose x: [b][c][p] -> [b][p][c], LDS-tiled -----------
__global__ __launch_bounds__(256) void transpose_kernel(
    const float* __restrict__ x, float* __restrict__ x_t) {
  __shared__ float tile[128][123];
  int b = blockIdx.x, t = threadIdx.x;
  const float* xb = x + (size_t)b * 128 * 121;
  for (int idx = t; idx < 128 * 121; idx += 256) {
    int c = idx / 121, p = idx - c * 121;
    tile[c][p] = xb[idx];
  }
  __syncthreads();
  float* ob = x_t + (size_t)b * 121 * 128;
  for (int idx = t; idx < 121 * 128; idx += 256) {
    int p = idx >> 7, c = idx & 127;
    ob[idx] = tile[c][p];
  }
}

// ---------------- softmax over last dim of cpr_w (48 rows x 128) -----------
__global__ __launch_bounds__(128) void softmax_kernel(
    const float* __restrict__ w, float* __restrict__ a) {
  int row = blockIdx.x, t = threadIdx.x;
  __shared__ float red[128];
  float v = w[row * 128 + t];
  red[t] = v;
  __syncthreads();
  for (int s = 64; s; s >>= 1) {
    if (t < s) red[t] = fmaxf(red[t], red[t + s]);
    __syncthreads();
  }
  float m = red[0];
  __syncthreads();
  float e = expf(v - m);
  red[t] = e;
  __syncthreads();
  for (int s = 64; s; s >>= 1) {
    if (t < s) red[t] += red[t + s];
    __syncthreads();
  }
  a[row * 128 + t] = e / red[0];
}

// ---------------- repack conv1 weights + conv2d45 weights ------------------
// wrep1: [g2][kd7][kh3][o8][kw3]; wrep2d: [layer2][ic16][uv9][o16]
__global__ __launch_bounds__(256) void repack1_kernel(
    const float* __restrict__ w3d1, const float* __restrict__ w2d45,
    float* __restrict__ wrep1, float* __restrict__ wrep2d) {
  int r = blockIdx.x * 256 + threadIdx.x;
  if (r < 1008) {
    int j = r;
    int kw = j % 3; j /= 3;
    int o = j % 8; j /= 8;
    int kh = j % 3; j /= 3;
    int kd = j % 7; j /= 7;
    int gg = j;
    wrep1[r] = w3d1[(gg * 8 + o) * 63 + kd * 9 + kh * 3 + kw];
  } else if (r < 1008 + 4608) {
    int r2 = r - 1008;
    int o = r2 & 15;
    int uv = (r2 >> 4) % 9;
    int ic = (r2 / 144) % 16;
    int layer = r2 / 2304;
    wrep2d[r2] = w2d45[((layer * 16 + o) * 16 + ic) * 9 + uv];
  }
}

// ---------------- repack conv2/3 weights into MFMA A-frag layout -----------
// arep[cv 2][chunk 36][part 2][lane 64][j 8] f16, scaled x256.
// chunk = (kh*4 + kdp)*3 + kw; k 0..15 -> kd=2kdp, k 16..31 -> kd=2kdp+1
// (kd=7 zero). lane: m=oc=lane&15, q=lane>>4; kd-half = q>>1, ic-half = q&1.
__global__ __launch_bounds__(256) void arep_kernel(
    const float* __restrict__ w3d23, unsigned short* __restrict__ arep) {
  int idx = blockIdx.x * 256 + threadIdx.x;  // 0..73727
  if (idx >= 2 * AREP_CV) return;
  int j = idx & 7;
  int lane = (idx >> 3) & 63;
  int part = (idx >> 9) & 1;
  int rem = idx >> 10;  // 0..71
  int chunk = rem % 36;
  int cv = rem / 36;
  int kw = chunk % 3;
  int grp = chunk / 3;
  int kdp = grp & 3;
  int kh = grp >> 2;
  int m = lane & 15, q = lane >> 4;
  int kd = 2 * kdp + (q >> 1);
  int ic = (q & 1) * 8 + j;
  float w = 0.f;
  if (kd < 7)
    w = w3d23[((cv * 16 + m) * 16 + ic) * 63 + kd * 9 + kh * 3 + kw] * 256.f;
  _Float16 hi = (_Float16)w;
  HU out;
  out.h = (part == 0) ? hi : (_Float16)(w - (float)hi);
  arep[idx] = out.u;
}

// ---------------- conv1 (ic=1) fp32: x_t -> pk1 planes (+cpr f1, +zerof) ---
__global__ __launch_bounds__(256, 4) void conv1_kernel(
    const float* __restrict__ in, const float* __restrict__ wrep,
    const float* __restrict__ bias, const float* __restrict__ al,
    unsigned short* __restrict__ pk_hi, unsigned short* __restrict__ pk_lo,
    float* __restrict__ f_out, float* __restrict__ f_zero) {
  __shared__ float in_lds[18][134];
  __shared__ float red[2][16][4];
  const int t = threadIdx.x;
  const int bx = blockIdx.x;
  const int b = blockIdx.y;
  const int h = bx / 3;
  const int w0 = (bx % 3) * 4;
  const int lane = t & 63;
  const int wv = t >> 6;
  const int dh = wv & 1;
  const int dd = lane + (dh << 6);
  const int g = __builtin_amdgcn_readfirstlane(wv >> 1);
  const int oc_base = g << 3;

  // fused zero of f_all slices 1,2 (atomic targets of the conv_mfma cpr)
  {
    int gid = (b * 33 + bx) * 256 + t;  // 540672 threads >= 2*F_SLICE
    if (gid < 2 * F_SLICE) f_zero[gid] = 0.f;
  }

  float acc[8][4];
#pragma unroll
  for (int o = 0; o < 8; ++o)
#pragma unroll
    for (int c = 0; c < 4; ++c) acc[o][c] = 0.f;

  const int ds = t & 127;
  const int half = t >> 7;

  for (int r = half; r < 18; r += 2) {
    int hr = r / 6;
    int wc = r - hr * 6;
    int hh = h - 1 + hr;
    int ww = w0 - 1 + wc;
    bool ok = (hh >= 0) & (hh < 11) & (ww >= 0) & (ww < 11);
    const float* src = in + (((size_t)b) * 121 + hh * 11 + ww) * 128;
    float v = 0.f;
    if (ok && ds >= 3) v = src[ds - 3];
    in_lds[r][ds] = v;
    if (ds < 6) {
      float v2 = 0.f;
      if (ok && ds < 3) v2 = src[125 + ds];
      in_lds[r][128 + ds] = v2;
    }
  }
  __syncthreads();
  const float* wbase = wrep + g * 504;
#pragma unroll
  for (int kd = 0; kd < 7; ++kd) {
#pragma unroll
    for (int kh = 0; kh < 3; ++kh) {
      float ws[24];
      const float* wp = wbase + kd * 72 + kh * 24;
#pragma unroll
      for (int j = 0; j < 24; ++j) ws[j] = wp[j];
      float v[6];
#pragma unroll
      for (int qq = 0; qq < 6; ++qq) v[qq] = in_lds[kh * 6 + qq][dd + kd];
#pragma unroll
      for (int o = 0; o < 8; ++o)
#pragma unroll
        for (int kw = 0; kw < 3; ++kw) {
          float wv_ = ws[o * 3 + kw];
#pragma unroll
          for (int c = 0; c < 4; ++c)
            acc[o][c] = fmaf(wv_, v[kw + c], acc[o][c]);
        }
    }
  }

  const int p0 = h * 11 + w0;
#pragma unroll
  for (int o = 0; o < 8; ++o) {
    float bv = bias[oc_base + o];
#pragma unroll
    for (int c = 0; c < 4; ++c) acc[o][c] = fmaxf(acc[o][c] + bv, 0.f);
  }
#pragma unroll
  for (int c = 0; c < 4; ++c) {
    if (w0 + c < 11) {
      u16x8 hi8, lo8;
#pragma unroll
      for (int o = 0; o < 8; ++o) {
        float s = acc[o][c] * 256.f;
        _Float16 hh = (_Float16)s;
        HU a, bb;
        a.h = hh;
        bb.h = (_Float16)(s - (float)hh);
        hi8[o] = a.u;
        lo8[o] = bb.u;
      }
      size_t base = (((size_t)b * 121 + p0 + c) * 134 + dd + 3) * 16 + oc_base;
      *(u16x8*)&pk_hi[base] = hi8;
      *(u16x8*)&pk_lo[base] = lo8;
    }
  }
  if (dd < 3) {
    u16x8 z = {0, 0, 0, 0, 0, 0, 0, 0};
#pragma unroll
    for (int c = 0; c < 4; ++c) {
      if (w0 + c < 11) {
        size_t b0 = (((size_t)b * 121 + p0 + c) * 134 + dd) * 16 + oc_base;
        size_t b1 =
            (((size_t)b * 121 + p0 + c) * 134 + 131 + dd) * 16 + oc_base;
        *(u16x8*)&pk_hi[b0] = z;
        *(u16x8*)&pk_lo[b0] = z;
        *(u16x8*)&pk_hi[b1] = z;
        *(u16x8*)&pk_lo[b1] = z;
      }
    }
  }
  float alv[8];
#pragma unroll
  for (int o = 0; o < 8; ++o) alv[o] = al[(oc_base + o) * 128 + dd];
#pragma unroll
  for (int o = 0; o < 8; ++o) {
#pragma unroll
    for (int c = 0; c < 4; ++c) {
      float pv = acc[o][c] * alv[o];
#pragma unroll
      for (int off = 32; off; off >>= 1) pv += __shfl_down(pv, off, 64);
      if (lane == 0) red[dh][oc_base + o][c] = pv;
    }
  }
  __syncthreads();
  if (t < 64) {
    int oc = t >> 2, c = t & 3;
    if (w0 + c < 11)
      f_out[((size_t)b * 16 + oc) * 121 + p0 + c] =
          fmaxf(red[0][oc][c] + red[1][oc][c], 0.f);
  }
}

// ---------------- conv2/conv3: MFMA f16x2-split, window-reuse K-loop -------
// Block = (bx h-pair, d16, b), 512 thr = 8 waves: hs = wave>>2, wg = wave&3.
// LDS: two part planes of 18304 halves; unit u (0..4575) at bytes u*16:
// u = part*2288 + (panel*2+icq)*22 + dloc, panel = rr*13+cc (4 rows x 13 w).
// Staging via global_load_lds (wave-uniform base + lane*16 == u*16).
template <bool WRITE_PK>
__global__ __launch_bounds__(512, 2) void conv_mfma_kernel(
    const unsigned short* __restrict__ pin_hi,
    const unsigned short* __restrict__ pin_lo,
    const unsigned short* __restrict__ arep, const float* __restrict__ bias,
    const float* __restrict__ al, unsigned short* __restrict__ pout_hi,
    unsigned short* __restrict__ pout_lo, float* __restrict__ f_out) {
  __shared__ _Float16 lds[2 * LHALF];
  const int t = threadIdx.x;
  const int bx = blockIdx.x, d16 = blockIdx.y, b = blockIdx.z;
  const int lane = t & 63, wave = t >> 6;
  const int n = lane & 15, q = lane >> 4;
  const int hs = wave >> 2, wg = wave & 3;
  const int h = 2 * bx + hs;  // 0..11 (11 = dummy)

  // ---- staging: 4576 16-B units; async DMA to LDS, halo lanes pre-zero ----
#pragma unroll
  for (int i = 0; i < 9; ++i) {
    int u = t + i * 512;
    int lbo = __builtin_amdgcn_readfirstlane((wave << 6) + i * 512);
    if (u < 4576) {
      int part = (u >= 2288) ? 1 : 0;
      int qq = u - part * 2288;
      int pc = qq / 22;
      int dloc = qq - pc * 22;
      int panel = pc >> 1, icq = pc & 1;
      int rr = panel / 13, cc = panel - rr * 13;
      int hh = 2 * bx + rr - 1, ww = cc - 1;
      bool ok = (hh >= 0) & (hh < 11) & (ww >= 0) & (ww < 11);
      if (ok) {
        const unsigned short* srcp = part ? pin_lo : pin_hi;
        const unsigned short* g =
            &srcp[(((size_t)b * 121 + hh * 11 + ww) * 134 + d16 * 16 + dloc) *
                      16 +
                  icq * 8];
        __builtin_amdgcn_global_load_lds((const gu32*)g,
                                         (lu32*)&lds[(size_t)lbo * 8], 16, 0,
                                         0);
      } else {
        u16x8 z = {0, 0, 0, 0, 0, 0, 0, 0};
        *(u16x8*)&lds[(size_t)u * 8] = z;
      }
    }
  }
  float bias_r[4], alr[4];
#pragma unroll
  for (int r = 0; r < 4; ++r) {
    bias_r[r] = bias[q * 4 + r];
    alr[r] = al[(q * 4 + r) * 128 + d16 * 16 + n];
  }
  __syncthreads();

  // ---- compute: window-reuse over (kh, kd-pair) groups ----
  const int wl0 = wg * 3;
  int cb[5], cbk[5];
  const int base_qn = (q & 1) * 176 + n * 8 + hs * 4576;
  const int kdh = (lane & 32) ? 8 : 0;
#pragma unroll
  for (int j = 0; j < 5; ++j) {
    int colj = wl0 + j;
    if (colj > 12) colj = 12;  // dummy-only column, result discarded
    cb[j] = base_qn + colj * 352;
    cbk[j] = cb[j] + kdh;
  }

  float4v acc[3];
#pragma unroll
  for (int tt = 0; tt < 3; ++tt) acc[tt] = (float4v){0.f, 0.f, 0.f, 0.f};

#pragma unroll
  for (int kh = 0; kh < 3; ++kh) {
#pragma unroll
    for (int kdp = 0; kdp < 4; ++kdp) {
      half8 whi[5], wlo[5];
#pragma unroll
      for (int j = 0; j < 5; ++j) {
        // kdp==3 pairs kd6 with zero kd7: both halves read kd6 (A half = 0)
        int a = ((kdp < 3) ? cbk[j] : cb[j]) + kh * 4576 + kdp * 16;
        whi[j] = *(const half8*)&lds[a];
        wlo[j] = *(const half8*)&lds[a + LHALF];
      }
#pragma unroll
      for (int kw = 0; kw < 3; ++kw) {
        const int c2 = (kh * 4 + kdp) * 3 + kw;
        half8 ahi = *(const half8*)&arep[((c2 * 2 + 0) * 64 + lane) * 8];
        half8 alo = *(const half8*)&arep[((c2 * 2 + 1) * 64 + lane) * 8];
#pragma unroll
        for (int tt = 0; tt < 3; ++tt) {
          const int jj = tt + kw;
          acc[tt] = __builtin_amdgcn_mfma_f32_16x16x32_f16(ahi, whi[jj],
                                                           acc[tt], 0, 0, 0);
          acc[tt] = __builtin_amdgcn_mfma_f32_16x16x32_f16(ahi, wlo[jj],
                                                           acc[tt], 0, 0, 0);
          acc[tt] = __builtin_amdgcn_mfma_f32_16x16x32_f16(alo, whi[jj],
                                                           acc[tt], 0, 0, 0);
        }
      }
    }
  }

  // ---- epilogue ----
#pragma unroll
  for (int tt = 0; tt < 3; ++tt) {
    const int wl = wg * 3 + tt;
    if (h < 11 && wl < 11) {
      const int p = h * 11 + wl;
      float fr[4];
      u16x4 hi4, lo4;
#pragma unroll
      for (int r = 0; r < 4; ++r) {
        float sv = fmaxf(acc[tt][r] * (1.f / 65536.f) + bias_r[r], 0.f);
        fr[r] = sv * alr[r];
        if (WRITE_PK) {
          float s = sv * 256.f;
          _Float16 hh = (_Float16)s;
          HU a, bb;
          a.h = hh;
          bb.h = (_Float16)(s - (float)hh);
          hi4[r] = a.u;
          lo4[r] = bb.u;
        }
      }
      if (WRITE_PK) {
        size_t base =
            (((size_t)b * 121 + p) * 134 + d16 * 16 + n + 3) * 16 + q * 4;
        *(u16x4*)&pout_hi[base] = hi4;
        *(u16x4*)&pout_lo[base] = lo4;
        u16x4 z = {0, 0, 0, 0};
        if (d16 == 0 && n < 3) {
          size_t hb = (((size_t)b * 121 + p) * 134 + n) * 16 + q * 4;
          *(u16x4*)&pout_hi[hb] = z;
          *(u16x4*)&pout_lo[hb] = z;
        }
        if (d16 == 7 && n >= 13) {
          size_t hb = (((size_t)b * 121 + p) * 134 + n + 118) * 16 + q * 4;
          *(u16x4*)&pout_hi[hb] = z;
          *(u16x4*)&pout_lo[hb] = z;
        }
      }
      // cpr partial: reduce over the 16 d's (n-lanes) of this block
#pragma unroll
      for (int r = 0; r < 4; ++r) {
        float v = fr[r];
        v += __shfl_xor(v, 1, 64);
        v += __shfl_xor(v, 2, 64);
        v += __shfl_xor(v, 4, 64);
        v += __shfl_xor(v, 8, 64);
        if (n == 0)
          atomicAdd(&f_out[((size_t)b * 16 + q * 4 + r) * 121 + p], v);
      }
    }
  }
}

// ---------------- both 16->16 2D convs (3x3 pad1 + relu), fused ------------
// input f3 is a raw atomic-accumulated sum -> apply relu on load.
// weights pre-repacked [layer][ic][uv][o16] -> batched wave-uniform s_loads.
__global__ __launch_bounds__(128) void conv2d2_kernel(
    const float* __restrict__ fin, const float* __restrict__ wrep2d,
    const float* __restrict__ bias, float* __restrict__ f4,
    float* __restrict__ f5) {
  const int b = blockIdx.x, t = threadIdx.x;
  __shared__ float buf0[16 * 121];
  __shared__ float buf1[16 * 121];
  const float* fb = fin + (size_t)b * 16 * 121;
  for (int idx = t; idx < 16 * 121; idx += 128)
    buf0[idx] = fmaxf(fb[idx], 0.f);
  __syncthreads();
  for (int layer = 0; layer < 2; ++layer) {
    const float* src = layer ? buf1 : buf0;
    float* dst = layer ? nullptr : buf1;
    const float* bl = bias + layer * 16;
    float* go = (layer ? f5 : f4) + (size_t)b * 16 * 121;
    if (t < 121) {
      int h = t / 11, w = t - h * 11;
      float acc[16];
#pragma unroll
      for (int o = 0; o < 16; ++o) acc[o] = bl[o];
      for (int ic = 0; ic < 16; ++ic) {
#pragma unroll
        for (int u = 0; u < 3; ++u) {
          int hh = h + u - 1;
#pragma unroll
          for (int v = 0; v < 3; ++v) {
            int ww = w + v - 1;
            float val = (hh >= 0 && hh < 11 && ww >= 0 && ww < 11)
                            ? src[ic * 121 + hh * 11 + ww]
                            : 0.f;
            const float* wp =
                wrep2d + (((layer * 16 + ic) * 9) + u * 3 + v) * 16;
            float wreg[16];
#pragma unroll
            for (int o = 0; o < 16; ++o) wreg[o] = wp[o];
#pragma unroll
            for (int o = 0; o < 16; ++o) acc[o] = fmaf(val, wreg[o], acc[o]);
          }
        }
      }
#pragma unroll
      for (int o = 0; o < 16; ++o) {
        float r = fmaxf(acc[o], 0.f);
        go[o * 121 + t] = r;
        if (dst) dst[o * 121 + t] = r;
      }
    }
    __syncthreads();
  }
}

// ---------------- sp path: seg conv -> top5 -> patch convs -> side ---------
// f_all slices may be raw sums (i=1,2) -> relu on load (identity for others).
__global__ __launch_bounds__(128) void sp_prep_kernel(
    const float* __restrict__ f_all, const float* __restrict__ x_t,
    const float* __restrict__ seg_w, const float* __restrict__ seg_b,
    const float* __restrict__ sp_wa, const float* __restrict__ sp_ba,
    const float* __restrict__ sp_wb, const float* __restrict__ sp_bb,
    const float* __restrict__ sp_sw, const float* __restrict__ sp_sb,
    float* __restrict__ sp_sd) {
  const int b = blockIdx.x, i = blockIdx.y;
  const int t = threadIdx.x;
  __shared__ float fl[16 * 121];
  __shared__ float act[121];
  __shared__ float diffs[121];
  __shared__ int sel[5];
  __shared__ float s7[7], xc7[7];
  __shared__ float P[2][7][7];
  __shared__ float y1[16][9];
  __shared__ float y2[16];

  const float* fb = f_all + ((size_t)i * 64 + b) * 16 * 121;
  for (int idx = t; idx < 16 * 121; idx += 128)
    fl[idx] = fmaxf(fb[idx], 0.f);
  __syncthreads();

  if (t < 121) {
    int h = t / 11, w = t - h * 11;
    float a = seg_b[i];
    const float* sw = seg_w + i * 144;
    for (int ic = 0; ic < 16; ++ic) {
      float w9[9];
#pragma unroll
      for (int j = 0; j < 9; ++j) w9[j] = sw[ic * 9 + j];  // consecutive
#pragma unroll
      for (int u = 0; u < 3; ++u) {
        int hh = h + u - 1;
#pragma unroll
        for (int v = 0; v < 3; ++v) {
          int ww = w + v - 1;
          if (hh >= 0 && hh < 11 && ww >= 0 && ww < 11)
            a = fmaf(fl[ic * 121 + hh * 11 + ww], w9[u * 3 + v], a);
        }
      }
    }
    act[t] = a;
  }
  __syncthreads();
  if (t < 121) diffs[t] = fabsf(act[t] - act[60]);
  __syncthreads();

  for (int k = 0; k < 5; ++k) {
    if (t < 64) {
      float d0 = diffs[t];
      int i0 = t;
      float d1 = (t + 64 < 121) ? diffs[t + 64] : 3.0e38f;
      if (d1 < d0) { d0 = d1; i0 = t + 64; }
#pragma unroll
      for (int off = 32; off; off >>= 1) {
        float od = __shfl_down(d0, off, 64);
        int oi = __shfl_down(i0, off, 64);
        if (od < d0 || (od == d0 && oi < i0)) { d0 = od; i0 = oi; }
      }
      if (t == 0) {
        sel[k] = i0;
        diffs[i0] = 3.0e38f;
      }
    }
    __syncthreads();
  }

  if (t < 7) {
    const float* xb = x_t + (size_t)b * 121 * 128;
    float s = 0.f;
    for (int k = 0; k < 5; ++k) s += xb[(size_t)sel[k] * 128 + 61 + t];
    s7[t] = s;
    xc7[t] = xb[60 * 128 + 61 + t];
  }
  __syncthreads();
  if (t < 49) {
    int r = t / 7, c = t - r * 7;
    float d0 = s7[c];
    if (fabsf(d0) < 0.01f) d0 = 0.01f;
    float d1 = xc7[c];
    if (fabsf(d1) < 0.01f) d1 = 0.01f;
    P[0][r][c] = s7[r] / d0;
    P[1][r][c] = xc7[r] / d1;
  }
  __syncthreads();
  for (int item = t; item < 144; item += 128) {
    int ch = item / 9, pos = item - ch * 9;
    int a0 = pos / 3, b0 = pos - a0 * 3;
    float a = sp_ba[i * 16 + ch];
    const float* wa = sp_wa + ((size_t)(i * 16 + ch) * 2) * 9;
#pragma unroll
    for (int icc = 0; icc < 2; ++icc)
#pragma unroll
      for (int u = 0; u < 3; ++u)
#pragma unroll
        for (int v = 0; v < 3; ++v)
          a = fmaf(P[icc][2 * a0 + u][2 * b0 + v], wa[icc * 9 + u * 3 + v], a);
    y1[ch][pos] = fmaxf(a, 0.f);
  }
  __syncthreads();
  if (t < 16) {
    float a = sp_bb[i * 16 + t];
    const float* wb = sp_wb + (size_t)(i * 16 + t) * 16 * 9;
    for (int ch = 0; ch < 16; ++ch)
#pragma unroll
      for (int pos = 0; pos < 9; ++pos)
        a = fmaf(y1[ch][pos], wb[ch * 9 + pos], a);
    y2[t] = fmaxf(a, 0.f);
  }
  __syncthreads();
  if (t < 16) {
    float a = sp_sb[i * 16 + t];
    const float* swp = sp_sw + (size_t)(i * 16 + t) * 16;
    for (int ch = 0; ch < 16; ++ch) a = fmaf(y2[ch], swp[ch], a);
    sp_sd[((size_t)i * 64 + b) * 16 + t] = a;
  }
}

// ---------------- final fuse (relu on center reads — exact for all feats) --
__global__ __launch_bounds__(256) void fuse_kernel(
    const float* __restrict__ f_all, const float* __restrict__ sp_sd,
    const float* __restrict__ so_w, const float* __restrict__ so_b,
    const float* __restrict__ fp, float* __restrict__ out) {
  int g = blockIdx.x * 256 + threadIdx.x;
  if (g >= 1024) return;
  int b = g >> 4, o = g & 15;
  float tot = 0.f;
  for (int i = 0; i < 5; ++i) {
    float s = so_b[i * 16 + o];
    for (int c = 0; c < 16; ++c)
      s += fmaxf(f_all[(((size_t)i * 64 + b) * 16 + c) * 121 + 60], 0.f) *
           so_w[(i * 16 + o) * 16 + c];
    tot += fp[i] * s;
    tot += fp[5 + i] * sp_sd[((size_t)i * 64 + b) * 16 + o];
  }
  out[g] = tot;
}

extern "C" void kernel_launch(void* const* d_in, const int* in_sizes, int n_in,
                              void* d_out, int out_size, void* d_ws,
                              size_t ws_size, hipStream_t stream) {
  const float* x = (const float*)d_in[0];
  const float* w3d1 = (const float*)d_in[1];
  const float* b3d1 = (const float*)d_in[2];
  const float* w3d23 = (const float*)d_in[3];
  const float* b3d23 = (const float*)d_in[4];
  const float* cpr_w = (const float*)d_in[5];
  const float* w2d45 = (const float*)d_in[6];
  const float* b2d45 = (const float*)d_in[7];
  const float* seg_w = (const float*)d_in[8];
  const float* seg_b = (const float*)d_in[9];
  const float* so_w = (const float*)d_in[10];
  const float* so_b = (const float*)d_in[11];
  const float* sp_wa = (const float*)d_in[12];
  const float* sp_ba = (const float*)d_in[13];
  const float* sp_wb = (const float*)d_in[14];
  const float* sp_bb = (const float*)d_in[15];
  const float* sp_sw = (const float*)d_in[16];
  const float* sp_sb = (const float*)d_in[17];
  const float* fpar = (const float*)d_in[18];

  float* ws = (float*)d_ws;
  float* x_t = ws;                       // 991232 f
  float* a_sm = x_t + 991232;            // 6144 f
  float* f_all = a_sm + 6144;            // 619520 f
  float* sp_sd = f_all + 619520;         // 5120 f
  float* wrep1 = sp_sd + 5120;           // 1024 f
  float* wrep2d = wrep1 + 1024;          // 4608 f
  unsigned short* pk1h = (unsigned short*)(wrep2d + 4608);
  unsigned short* pk1l = pk1h + PKE;
  unsigned short* pk2h = pk1l + PKE;
  unsigned short* pk2l = pk2h + PKE;
  unsigned short* arep = pk2l + PKE;     // 2*AREP_CV u16

  transpose_kernel<<<64, 256, 0, stream>>>(x, x_t);
  softmax_kernel<<<48, 128, 0, stream>>>(cpr_w, a_sm);
  repack1_kernel<<<22, 256, 0, stream>>>(w3d1, w2d45, wrep1, wrep2d);
  arep_kernel<<<288, 256, 0, stream>>>(w3d23, arep);

  conv1_kernel<<<dim3(33, 64), 256, 0, stream>>>(
      x_t, wrep1, b3d1, a_sm, pk1h, pk1l, f_all, f_all + F_SLICE);
  conv_mfma_kernel<true><<<dim3(6, 8, 64), 512, 0, stream>>>(
      pk1h, pk1l, arep, b3d23, a_sm + 2048, pk2h, pk2l, f_all + F_SLICE);
  conv_mfma_kernel<false><<<dim3(6, 8, 64), 512, 0, stream>>>(
      pk2h, pk2l, arep + AREP_CV, b3d23 + 16, a_sm + 4096, nullptr, nullptr,
      f_all + 2 * F_SLICE);

  conv2d2_kernel<<<64, 128, 0, stream>>>(f_all + 2 * F_SLICE, wrep2d, b2d45,
                                         f_all + 3 * F_SLICE,
                                         f_all + 4 * F_SLICE);

  sp_prep_kernel<<<dim3(64, 5), 128, 0, stream>>>(
      f_all, x_t, seg_w, seg_b, sp_wa, sp_ba, sp_wb, sp_bb, sp_sw, sp_sb,
      sp_sd);
  fuse_kernel<<<4, 256, 0, stream>>>(f_all, sp_sd, so_w, so_b, fpar,
                                     (float*)d_out);
}

// Round 11
// 446.380 us; speedup vs baseline: 3.1093x; 1.0871x over previous
//
#include <hip/hip_runtime.h>
#include <hip/hip_bf16.h>

// ---------------------------------------------------------------------------
// Segment_3DCenter round 11: round-10 structure, with DETERMINISTIC cpr:
// conv_mfma writes per-d16 partial sums to fpart[d16][b][oc][p] (each slot
// written exactly once; no atomics), and sp_prep reduces the 8 slices in
// fixed d16 order on load. Fixes the replay-nondeterminism (float atomicAdd
// ordering flipped a near-tied top-5 selection). Also drops conv1's fused
// zeroing (no atomic targets remain).
// ---------------------------------------------------------------------------

#define F_SLICE (64 * 16 * 121)          // 123904
#define PKE (64 * 121 * 134 * 16)        // u16 elements per pk plane
#define LHALF 18304                      // LDS halves per part (52*352)
#define AREP_CV 36864                    // u16 per conv in arep (36*2*64*8)

typedef _Float16 half8 __attribute__((ext_vector_type(8)));
typedef float float4v __attribute__((ext_vector_type(4)));
typedef unsigned short u16x8 __attribute__((ext_vector_type(8)));
typedef unsigned short u16x4 __attribute__((ext_vector_type(4)));

typedef __attribute__((address_space(1))) unsigned int gu32;
typedef __attribute__((address_space(3))) unsigned int lu32;

union HU { _Float16 h; unsigned short u; };

// ---------------- prep: transpose + softmax + repacks + arep ---------------
__global__ __launch_bounds__(256) void prep_kernel(
    const float* __restrict__ x, const float* __restrict__ cpr_w,
    const float* __restrict__ w3d1, const float* __restrict__ w2d45,
    const float* __restrict__ w3d23, float* __restrict__ x_t,
    float* __restrict__ a_sm, float* __restrict__ wrep1,
    float* __restrict__ wrep2d, unsigned short* __restrict__ arep) {
  const int bx = blockIdx.x, t = threadIdx.x;
  if (bx < 64) {
    __shared__ float tile[128][123];
    const int b = bx;
    const float* xb = x + (size_t)b * 128 * 121;
    for (int idx = t; idx < 128 * 121; idx += 256) {
      int c = idx / 121, p = idx - c * 121;
      tile[c][p] = xb[idx];
    }
    __syncthreads();
    float* ob = x_t + (size_t)b * 121 * 128;
    for (int idx = t; idx < 121 * 128; idx += 256) {
      int p = idx >> 7, c = idx & 127;
      ob[idx] = tile[c][p];
    }
  } else if (bx < 112) {
    __shared__ float red[128];
    const int row = bx - 64;
    float v = (t < 128) ? cpr_w[row * 128 + t] : -3.0e38f;
    if (t < 128) red[t] = v;
    __syncthreads();
    for (int s = 64; s; s >>= 1) {
      if (t < s) red[t] = fmaxf(red[t], red[t + s]);
      __syncthreads();
    }
    float m = red[0];
    __syncthreads();
    float e = (t < 128) ? expf(v - m) : 0.f;
    if (t < 128) red[t] = e;
    __syncthreads();
    for (int s = 64; s; s >>= 1) {
      if (t < s) red[t] += red[t + s];
      __syncthreads();
    }
    if (t < 128) a_sm[row * 128 + t] = e / red[0];
  } else if (bx < 134) {
    int r = (bx - 112) * 256 + t;
    if (r < 1008) {
      int j = r;
      int kw = j % 3; j /= 3;
      int o = j % 8; j /= 8;
      int kh = j % 3; j /= 3;
      int kd = j % 7; j /= 7;
      int gg = j;
      wrep1[r] = w3d1[(gg * 8 + o) * 63 + kd * 9 + kh * 3 + kw];
    } else if (r < 1008 + 4608) {
      int r2 = r - 1008;
      int o = r2 & 15;
      int uv = (r2 >> 4) % 9;
      int ic = (r2 / 144) % 16;
      int layer = r2 / 2304;
      wrep2d[r2] = w2d45[((layer * 16 + o) * 16 + ic) * 9 + uv];
    }
  } else {
    int idx = (bx - 134) * 256 + t;
    if (idx < 2 * AREP_CV) {
      int j = idx & 7;
      int lane = (idx >> 3) & 63;
      int part = (idx >> 9) & 1;
      int rem = idx >> 10;
      int chunk = rem % 36;
      int cv = rem / 36;
      int kw = chunk % 3;
      int grp = chunk / 3;
      int kdp = grp & 3;
      int kh = grp >> 2;
      int m = lane & 15, q = lane >> 4;
      int kd = 2 * kdp + (q >> 1);
      int ic = (q & 1) * 8 + j;
      float w = 0.f;
      if (kd < 7)
        w = w3d23[((cv * 16 + m) * 16 + ic) * 63 + kd * 9 + kh * 3 + kw] *
            256.f;
      _Float16 hi = (_Float16)w;
      HU out;
      out.h = (part == 0) ? hi : (_Float16)(w - (float)hi);
      arep[idx] = out.u;
    }
  }
}

// ---------------- conv1 (ic=1) fp32: x_t -> pk1 planes (+fused cpr f1) -----
__global__ __launch_bounds__(256, 4) void conv1_kernel(
    const float* __restrict__ in, const float* __restrict__ wrep,
    const float* __restrict__ bias, const float* __restrict__ al,
    unsigned short* __restrict__ pk_hi, unsigned short* __restrict__ pk_lo,
    float* __restrict__ f_out) {
  __shared__ float in_lds[18][134];
  __shared__ float red[2][16][4];
  const int t = threadIdx.x;
  const int bx = blockIdx.x;
  const int b = blockIdx.y;
  const int h = bx / 3;
  const int w0 = (bx % 3) * 4;
  const int lane = t & 63;
  const int wv = t >> 6;
  const int dh = wv & 1;
  const int dd = lane + (dh << 6);
  const int g = __builtin_amdgcn_readfirstlane(wv >> 1);
  const int oc_base = g << 3;

  float acc[8][4];
#pragma unroll
  for (int o = 0; o < 8; ++o)
#pragma unroll
    for (int c = 0; c < 4; ++c) acc[o][c] = 0.f;

  const int ds = t & 127;
  const int half = t >> 7;

  for (int r = half; r < 18; r += 2) {
    int hr = r / 6;
    int wc = r - hr * 6;
    int hh = h - 1 + hr;
    int ww = w0 - 1 + wc;
    bool ok = (hh >= 0) & (hh < 11) & (ww >= 0) & (ww < 11);
    const float* src = in + (((size_t)b) * 121 + hh * 11 + ww) * 128;
    float v = 0.f;
    if (ok && ds >= 3) v = src[ds - 3];
    in_lds[r][ds] = v;
    if (ds < 6) {
      float v2 = 0.f;
      if (ok && ds < 3) v2 = src[125 + ds];
      in_lds[r][128 + ds] = v2;
    }
  }
  __syncthreads();
  const float* wbase = wrep + g * 504;
#pragma unroll
  for (int kd = 0; kd < 7; ++kd) {
#pragma unroll
    for (int kh = 0; kh < 3; ++kh) {
      float ws[24];
      const float* wp = wbase + kd * 72 + kh * 24;
#pragma unroll
      for (int j = 0; j < 24; ++j) ws[j] = wp[j];
      float v[6];
#pragma unroll
      for (int qq = 0; qq < 6; ++qq) v[qq] = in_lds[kh * 6 + qq][dd + kd];
#pragma unroll
      for (int o = 0; o < 8; ++o)
#pragma unroll
        for (int kw = 0; kw < 3; ++kw) {
          float wv_ = ws[o * 3 + kw];
#pragma unroll
          for (int c = 0; c < 4; ++c)
            acc[o][c] = fmaf(wv_, v[kw + c], acc[o][c]);
        }
    }
  }

  const int p0 = h * 11 + w0;
#pragma unroll
  for (int o = 0; o < 8; ++o) {
    float bv = bias[oc_base + o];
#pragma unroll
    for (int c = 0; c < 4; ++c) acc[o][c] = fmaxf(acc[o][c] + bv, 0.f);
  }
#pragma unroll
  for (int c = 0; c < 4; ++c) {
    if (w0 + c < 11) {
      u16x8 hi8, lo8;
#pragma unroll
      for (int o = 0; o < 8; ++o) {
        float s = acc[o][c] * 256.f;
        _Float16 hh = (_Float16)s;
        HU a, bb;
        a.h = hh;
        bb.h = (_Float16)(s - (float)hh);
        hi8[o] = a.u;
        lo8[o] = bb.u;
      }
      size_t base = (((size_t)b * 121 + p0 + c) * 134 + dd + 3) * 16 + oc_base;
      *(u16x8*)&pk_hi[base] = hi8;
      *(u16x8*)&pk_lo[base] = lo8;
    }
  }
  if (dd < 3) {
    u16x8 z = {0, 0, 0, 0, 0, 0, 0, 0};
#pragma unroll
    for (int c = 0; c < 4; ++c) {
      if (w0 + c < 11) {
        size_t b0 = (((size_t)b * 121 + p0 + c) * 134 + dd) * 16 + oc_base;
        size_t b1 =
            (((size_t)b * 121 + p0 + c) * 134 + 131 + dd) * 16 + oc_base;
        *(u16x8*)&pk_hi[b0] = z;
        *(u16x8*)&pk_lo[b0] = z;
        *(u16x8*)&pk_hi[b1] = z;
        *(u16x8*)&pk_lo[b1] = z;
      }
    }
  }
  float alv[8];
#pragma unroll
  for (int o = 0; o < 8; ++o) alv[o] = al[(oc_base + o) * 128 + dd];
#pragma unroll
  for (int o = 0; o < 8; ++o) {
#pragma unroll
    for (int c = 0; c < 4; ++c) {
      float pv = acc[o][c] * alv[o];
#pragma unroll
      for (int off = 32; off; off >>= 1) pv += __shfl_down(pv, off, 64);
      if (lane == 0) red[dh][oc_base + o][c] = pv;
    }
  }
  __syncthreads();
  if (t < 64) {
    int oc = t >> 2, c = t & 3;
    if (w0 + c < 11)
      f_out[((size_t)b * 16 + oc) * 121 + p0 + c] =
          fmaxf(red[0][oc][c] + red[1][oc][c], 0.f);
  }
}

// ---------------- conv2/conv3: MFMA f16x2-split, window-reuse K-loop -------
// cpr partials -> fpart[d16][b][oc][p] (deterministic; each slot written once)
template <bool WRITE_PK>
__global__ __launch_bounds__(512, 2) void conv_mfma_kernel(
    const unsigned short* __restrict__ pin_hi,
    const unsigned short* __restrict__ pin_lo,
    const unsigned short* __restrict__ arep, const float* __restrict__ bias,
    const float* __restrict__ al, unsigned short* __restrict__ pout_hi,
    unsigned short* __restrict__ pout_lo, float* __restrict__ fpart) {
  __shared__ _Float16 lds[2 * LHALF];
  const int t = threadIdx.x;
  const int bx = blockIdx.x, d16 = blockIdx.y, b = blockIdx.z;
  const int lane = t & 63, wave = t >> 6;
  const int n = lane & 15, q = lane >> 4;
  const int hs = wave >> 2, wg = wave & 3;
  const int h = 2 * bx + hs;  // 0..11 (11 = dummy)

#pragma unroll
  for (int i = 0; i < 9; ++i) {
    int u = t + i * 512;
    int lbo = __builtin_amdgcn_readfirstlane((wave << 6) + i * 512);
    if (u < 4576) {
      int part = (u >= 2288) ? 1 : 0;
      int qq = u - part * 2288;
      int pc = qq / 22;
      int dloc = qq - pc * 22;
      int panel = pc >> 1, icq = pc & 1;
      int rr = panel / 13, cc = panel - rr * 13;
      int hh = 2 * bx + rr - 1, ww = cc - 1;
      bool ok = (hh >= 0) & (hh < 11) & (ww >= 0) & (ww < 11);
      if (ok) {
        const unsigned short* srcp = part ? pin_lo : pin_hi;
        const unsigned short* g =
            &srcp[(((size_t)b * 121 + hh * 11 + ww) * 134 + d16 * 16 + dloc) *
                      16 +
                  icq * 8];
        __builtin_amdgcn_global_load_lds((const gu32*)g,
                                         (lu32*)&lds[(size_t)lbo * 8], 16, 0,
                                         0);
      } else {
        u16x8 z = {0, 0, 0, 0, 0, 0, 0, 0};
        *(u16x8*)&lds[(size_t)u * 8] = z;
      }
    }
  }
  float bias_r[4], alr[4];
#pragma unroll
  for (int r = 0; r < 4; ++r) {
    bias_r[r] = bias[q * 4 + r];
    alr[r] = al[(q * 4 + r) * 128 + d16 * 16 + n];
  }
  __syncthreads();

  const int wl0 = wg * 3;
  int cb[5], cbk[5];
  const int base_qn = (q & 1) * 176 + n * 8 + hs * 4576;
  const int kdh = (lane & 32) ? 8 : 0;
#pragma unroll
  for (int j = 0; j < 5; ++j) {
    int colj = wl0 + j;
    if (colj > 12) colj = 12;
    cb[j] = base_qn + colj * 352;
    cbk[j] = cb[j] + kdh;
  }

  float4v acc[3];
#pragma unroll
  for (int tt = 0; tt < 3; ++tt) acc[tt] = (float4v){0.f, 0.f, 0.f, 0.f};

#pragma unroll
  for (int kh = 0; kh < 3; ++kh) {
#pragma unroll
    for (int kdp = 0; kdp < 4; ++kdp) {
      half8 whi[5], wlo[5];
#pragma unroll
      for (int j = 0; j < 5; ++j) {
        int a = ((kdp < 3) ? cbk[j] : cb[j]) + kh * 4576 + kdp * 16;
        whi[j] = *(const half8*)&lds[a];
        wlo[j] = *(const half8*)&lds[a + LHALF];
      }
#pragma unroll
      for (int kw = 0; kw < 3; ++kw) {
        const int c2 = (kh * 4 + kdp) * 3 + kw;
        half8 ahi = *(const half8*)&arep[((c2 * 2 + 0) * 64 + lane) * 8];
        half8 alo = *(const half8*)&arep[((c2 * 2 + 1) * 64 + lane) * 8];
#pragma unroll
        for (int tt = 0; tt < 3; ++tt) {
          const int jj = tt + kw;
          acc[tt] = __builtin_amdgcn_mfma_f32_16x16x32_f16(ahi, whi[jj],
                                                           acc[tt], 0, 0, 0);
          acc[tt] = __builtin_amdgcn_mfma_f32_16x16x32_f16(ahi, wlo[jj],
                                                           acc[tt], 0, 0, 0);
          acc[tt] = __builtin_amdgcn_mfma_f32_16x16x32_f16(alo, whi[jj],
                                                           acc[tt], 0, 0, 0);
        }
      }
    }
  }

#pragma unroll
  for (int tt = 0; tt < 3; ++tt) {
    const int wl = wg * 3 + tt;
    if (h < 11 && wl < 11) {
      const int p = h * 11 + wl;
      float fr[4];
      u16x4 hi4, lo4;
#pragma unroll
      for (int r = 0; r < 4; ++r) {
        float sv = fmaxf(acc[tt][r] * (1.f / 65536.f) + bias_r[r], 0.f);
        fr[r] = sv * alr[r];
        if (WRITE_PK) {
          float s = sv * 256.f;
          _Float16 hh = (_Float16)s;
          HU a, bb;
          a.h = hh;
          bb.h = (_Float16)(s - (float)hh);
          hi4[r] = a.u;
          lo4[r] = bb.u;
        }
      }
      if (WRITE_PK) {
        size_t base =
            (((size_t)b * 121 + p) * 134 + d16 * 16 + n + 3) * 16 + q * 4;
        *(u16x4*)&pout_hi[base] = hi4;
        *(u16x4*)&pout_lo[base] = lo4;
        u16x4 z = {0, 0, 0, 0};
        if (d16 == 0 && n < 3) {
          size_t hb = (((size_t)b * 121 + p) * 134 + n) * 16 + q * 4;
          *(u16x4*)&pout_hi[hb] = z;
          *(u16x4*)&pout_lo[hb] = z;
        }
        if (d16 == 7 && n >= 13) {
          size_t hb = (((size_t)b * 121 + p) * 134 + n + 118) * 16 + q * 4;
          *(u16x4*)&pout_hi[hb] = z;
          *(u16x4*)&pout_lo[hb] = z;
        }
      }
      // cpr partial: reduce over the 16 d's of this block; one writer per slot
#pragma unroll
      for (int r = 0; r < 4; ++r) {
        float v = fr[r];
        v += __shfl_xor(v, 1, 64);
        v += __shfl_xor(v, 2, 64);
        v += __shfl_xor(v, 4, 64);
        v += __shfl_xor(v, 8, 64);
        if (n == 0)
          fpart[(((size_t)d16 * 64 + b) * 16 + q * 4 + r) * 121 + p] = v;
      }
    }
  }
}

// ---------------- sp path (+sa side-outs, +f4/f5 recompute in LDS) ---------
// grid (64 b, 5 i), 128 thr. F source:
//   i=0: f1 (dense, relu'd already)  i=1: sum_d16 fpart1 (fixed order)
//   i=2: sum fpart2                  i=3: conv_l0(sum fpart2)
//   i=4: conv_l1(conv_l0(sum fpart2))
__global__ __launch_bounds__(128) void sp_prep_kernel(
    const float* __restrict__ f1, const float* __restrict__ fpart1,
    const float* __restrict__ fpart2, const float* __restrict__ x_t,
    const float* __restrict__ wrep2d, const float* __restrict__ b2d45,
    const float* __restrict__ seg_w, const float* __restrict__ seg_b,
    const float* __restrict__ so_w, const float* __restrict__ so_b,
    const float* __restrict__ sp_wa, const float* __restrict__ sp_ba,
    const float* __restrict__ sp_wb, const float* __restrict__ sp_bb,
    const float* __restrict__ sp_sw, const float* __restrict__ sp_sb,
    float* __restrict__ sa_sd, float* __restrict__ sp_sd) {
  const int b = blockIdx.x, i = blockIdx.y;
  const int t = threadIdx.x;
  __shared__ float fl[16 * 121];
  __shared__ float buf[16 * 121];
  __shared__ float act[121];
  __shared__ float diffs[121];
  __shared__ int sel[5];
  __shared__ float s7[7], xc7[7];
  __shared__ float P[2][7][7];
  __shared__ float y1[16][9];
  __shared__ float y2[16];

  // load base feat
  {
    float* ldst = (i < 3) ? fl : buf;
    if (i == 0) {
      const float* fb = f1 + (size_t)b * 16 * 121;
      for (int idx = t; idx < 16 * 121; idx += 128) ldst[idx] = fb[idx];
    } else {
      const float* fp0 = (i == 1) ? fpart1 : fpart2;
      const size_t boff = (size_t)b * 16 * 121;
      for (int idx = t; idx < 16 * 121; idx += 128) {
        float s = 0.f;
#pragma unroll
        for (int d16 = 0; d16 < 8; ++d16)  // fixed order -> deterministic
          s += fp0[(size_t)d16 * F_SLICE + boff + idx];
        ldst[idx] = fmaxf(s, 0.f);
      }
    }
  }
  __syncthreads();

#define CONV2D_LAYER(SRC, DST, L)                                        \
  if (t < 121) {                                                         \
    int h_ = t / 11, w_ = t - h_ * 11;                                   \
    float a_[16];                                                        \
    _Pragma("unroll") for (int o = 0; o < 16; ++o) a_[o] =               \
        b2d45[(L)*16 + o];                                               \
    for (int ic = 0; ic < 16; ++ic) {                                    \
      _Pragma("unroll") for (int u = 0; u < 3; ++u) {                    \
        int hh_ = h_ + u - 1;                                            \
        _Pragma("unroll") for (int v = 0; v < 3; ++v) {                  \
          int ww_ = w_ + v - 1;                                          \
          float val_ = (hh_ >= 0 && hh_ < 11 && ww_ >= 0 && ww_ < 11)    \
                           ? (SRC)[ic * 121 + hh_ * 11 + ww_]            \
                           : 0.f;                                        \
          const float* wp_ =                                             \
              wrep2d + (((L)*16 + ic) * 9 + u * 3 + v) * 16;             \
          float wr_[16];                                                 \
          _Pragma("unroll") for (int o = 0; o < 16; ++o) wr_[o] = wp_[o];\
          _Pragma("unroll") for (int o = 0; o < 16; ++o) a_[o] =         \
              fmaf(val_, wr_[o], a_[o]);                                 \
        }                                                                \
      }                                                                  \
    }                                                                    \
    _Pragma("unroll") for (int o = 0; o < 16; ++o)(DST)[o * 121 + t] =   \
        fmaxf(a_[o], 0.f);                                               \
  }

  if (i >= 3) {
    CONV2D_LAYER(buf, fl, 0)
    __syncthreads();
    if (i == 4) {
      CONV2D_LAYER(fl, buf, 1)
      __syncthreads();
    }
  }
  const float* F = (i == 4) ? buf : fl;

  // sa side-output for (b, i)
  if (t < 16) {
    float s = so_b[i * 16 + t];
    const float* swp = so_w + (i * 16 + t) * 16;
    for (int c = 0; c < 16; ++c) s += F[c * 121 + 60] * swp[c];
    sa_sd[((size_t)i * 64 + b) * 16 + t] = s;
  }

  // seg conv (no relu)
  if (t < 121) {
    int h = t / 11, w = t - h * 11;
    float a = seg_b[i];
    const float* sw = seg_w + i * 144;
    for (int ic = 0; ic < 16; ++ic) {
      float w9[9];
#pragma unroll
      for (int j = 0; j < 9; ++j) w9[j] = sw[ic * 9 + j];
#pragma unroll
      for (int u = 0; u < 3; ++u) {
        int hh = h + u - 1;
#pragma unroll
        for (int v = 0; v < 3; ++v) {
          int ww = w + v - 1;
          if (hh >= 0 && hh < 11 && ww >= 0 && ww < 11)
            a = fmaf(F[ic * 121 + hh * 11 + ww], w9[u * 3 + v], a);
        }
      }
    }
    act[t] = a;
  }
  __syncthreads();
  if (t < 121) diffs[t] = fabsf(act[t] - act[60]);
  __syncthreads();

  for (int k = 0; k < 5; ++k) {
    if (t < 64) {
      float d0 = diffs[t];
      int i0 = t;
      float d1 = (t + 64 < 121) ? diffs[t + 64] : 3.0e38f;
      if (d1 < d0) { d0 = d1; i0 = t + 64; }
#pragma unroll
      for (int off = 32; off; off >>= 1) {
        float od = __shfl_down(d0, off, 64);
        int oi = __shfl_down(i0, off, 64);
        if (od < d0 || (od == d0 && oi < i0)) { d0 = od; i0 = oi; }
      }
      if (t == 0) {
        sel[k] = i0;
        diffs[i0] = 3.0e38f;
      }
    }
    __syncthreads();
  }

  if (t < 7) {
    const float* xb = x_t + (size_t)b * 121 * 128;
    float s = 0.f;
    for (int k = 0; k < 5; ++k) s += xb[(size_t)sel[k] * 128 + 61 + t];
    s7[t] = s;
    xc7[t] = xb[60 * 128 + 61 + t];
  }
  __syncthreads();
  if (t < 49) {
    int r = t / 7, c = t - r * 7;
    float d0 = s7[c];
    if (fabsf(d0) < 0.01f) d0 = 0.01f;
    float d1 = xc7[c];
    if (fabsf(d1) < 0.01f) d1 = 0.01f;
    P[0][r][c] = s7[r] / d0;
    P[1][r][c] = xc7[r] / d1;
  }
  __syncthreads();
  for (int item = t; item < 144; item += 128) {
    int ch = item / 9, pos = item - ch * 9;
    int a0 = pos / 3, b0 = pos - a0 * 3;
    float a = sp_ba[i * 16 + ch];
    const float* wa = sp_wa + ((size_t)(i * 16 + ch) * 2) * 9;
#pragma unroll
    for (int icc = 0; icc < 2; ++icc)
#pragma unroll
      for (int u = 0; u < 3; ++u)
#pragma unroll
        for (int v = 0; v < 3; ++v)
          a = fmaf(P[icc][2 * a0 + u][2 * b0 + v], wa[icc * 9 + u * 3 + v], a);
    y1[ch][pos] = fmaxf(a, 0.f);
  }
  __syncthreads();
  if (t < 16) {
    float a = sp_bb[i * 16 + t];
    const float* wb = sp_wb + (size_t)(i * 16 + t) * 16 * 9;
    for (int ch = 0; ch < 16; ++ch)
#pragma unroll
      for (int pos = 0; pos < 9; ++pos)
        a = fmaf(y1[ch][pos], wb[ch * 9 + pos], a);
    y2[t] = fmaxf(a, 0.f);
  }
  __syncthreads();
  if (t < 16) {
    float a = sp_sb[i * 16 + t];
    const float* swp = sp_sw + (size_t)(i * 16 + t) * 16;
    for (int ch = 0; ch < 16; ++ch) a = fmaf(y2[ch], swp[ch], a);
    sp_sd[((size_t)i * 64 + b) * 16 + t] = a;
  }
}

// ---------------- final fuse ------------------------------------------------
__global__ __launch_bounds__(256) void fuse_kernel(
    const float* __restrict__ sa_sd, const float* __restrict__ sp_sd,
    const float* __restrict__ fp, float* __restrict__ out) {
  int g = blockIdx.x * 256 + threadIdx.x;
  if (g >= 1024) return;
  int b = g >> 4, o = g & 15;
  float tot = 0.f;
  for (int i = 0; i < 5; ++i) {
    tot += fp[i] * sa_sd[((size_t)i * 64 + b) * 16 + o];
    tot += fp[5 + i] * sp_sd[((size_t)i * 64 + b) * 16 + o];
  }
  out[g] = tot;
}

extern "C" void kernel_launch(void* const* d_in, const int* in_sizes, int n_in,
                              void* d_out, int out_size, void* d_ws,
                              size_t ws_size, hipStream_t stream) {
  const float* x = (const float*)d_in[0];
  const float* w3d1 = (const float*)d_in[1];
  const float* b3d1 = (const float*)d_in[2];
  const float* w3d23 = (const float*)d_in[3];
  const float* b3d23 = (const float*)d_in[4];
  const float* cpr_w = (const float*)d_in[5];
  const float* w2d45 = (const float*)d_in[6];
  const float* b2d45 = (const float*)d_in[7];
  const float* seg_w = (const float*)d_in[8];
  const float* seg_b = (const float*)d_in[9];
  const float* so_w = (const float*)d_in[10];
  const float* so_b = (const float*)d_in[11];
  const float* sp_wa = (const float*)d_in[12];
  const float* sp_ba = (const float*)d_in[13];
  const float* sp_wb = (const float*)d_in[14];
  const float* sp_bb = (const float*)d_in[15];
  const float* sp_sw = (const float*)d_in[16];
  const float* sp_sb = (const float*)d_in[17];
  const float* fpar = (const float*)d_in[18];

  float* ws = (float*)d_ws;
  float* x_t = ws;                       // 991232 f
  float* a_sm = x_t + 991232;            // 6144 f
  float* f1 = a_sm + 6144;               // F_SLICE f
  float* fpart1 = f1 + F_SLICE;          // 8*F_SLICE f
  float* fpart2 = fpart1 + 8 * F_SLICE;  // 8*F_SLICE f
  float* sp_sd = fpart2 + 8 * F_SLICE;   // 5120 f
  float* sa_sd = sp_sd + 5120;           // 5120 f
  float* wrep1 = sa_sd + 5120;           // 1024 f
  float* wrep2d = wrep1 + 1024;          // 4608 f
  unsigned short* pk1h = (unsigned short*)(wrep2d + 4608);
  unsigned short* pk1l = pk1h + PKE;
  unsigned short* pk2h = pk1l + PKE;
  unsigned short* pk2l = pk2h + PKE;
  unsigned short* arep = pk2l + PKE;     // 2*AREP_CV u16

  prep_kernel<<<422, 256, 0, stream>>>(x, cpr_w, w3d1, w2d45, w3d23, x_t,
                                       a_sm, wrep1, wrep2d, arep);

  conv1_kernel<<<dim3(33, 64), 256, 0, stream>>>(x_t, wrep1, b3d1, a_sm, pk1h,
                                                 pk1l, f1);
  conv_mfma_kernel<true><<<dim3(6, 8, 64), 512, 0, stream>>>(
      pk1h, pk1l, arep, b3d23, a_sm + 2048, pk2h, pk2l, fpart1);
  conv_mfma_kernel<false><<<dim3(6, 8, 64), 512, 0, stream>>>(
      pk2h, pk2l, arep + AREP_CV, b3d23 + 16, a_sm + 4096, nullptr, nullptr,
      fpart2);

  sp_prep_kernel<<<dim3(64, 5), 128, 0, stream>>>(
      f1, fpart1, fpart2, x_t, wrep2d, b2d45, seg_w, seg_b, so_w, so_b,
      sp_wa, sp_ba, sp_wb, sp_bb, sp_sw, sp_sb, sa_sd, sp_sd);
  fuse_kernel<<<4, 256, 0, stream>>>(sa_sd, sp_sd, fpar, (float*)d_out);
}